// Round 11
// baseline (597.528 us; speedup 1.0000x reference)
//
#include <hip/hip_runtime.h>
#include <math.h>

#define NN 50000
#define EE 800000
#define FF 128

constexpr float LN_EPS = 1e-5f;
constexpr int NC = (NN + 255) / 256;   // 196 scan chunks

typedef float  f32x4  __attribute__((ext_vector_type(4)));
typedef short  s16x8  __attribute__((ext_vector_type(8)));
typedef unsigned short u16x4 __attribute__((ext_vector_type(4)));

__device__ __forceinline__ float silu_f(float v) {
    return v / (1.f + __expf(-v));
}

__device__ __forceinline__ unsigned short f2bf(float f) {
    union { float f; unsigned u; } cv; cv.f = f;
    unsigned u = cv.u;
    u += 0x7fffu + ((u >> 16) & 1u);   // round-to-nearest-even
    return (unsigned short)(u >> 16);
}

__device__ __forceinline__ float bf2f(unsigned short u) {
    union { unsigned u; float f; } cv; cv.u = ((unsigned)u) << 16;
    return cv.f;
}

// ---------- fused prep: x -> bf16  AND  weight transposes -> bf16 ----------
constexpr int CVT_BLKS = (NN * FF / 8) / 256;       // 3125
constexpr int TRW_BLKS = (32768 + 3 * 16384) / 256; // 320

__global__ __launch_bounds__(256) void prep_kernel(
    const float* __restrict__ x, unsigned short* __restrict__ xb,
    const float* __restrict__ ew1, const float* __restrict__ ew2,
    const float* __restrict__ nw1, const float* __restrict__ nw2,
    unsigned short* __restrict__ ew1T, unsigned short* __restrict__ ew2T,
    unsigned short* __restrict__ nw1T, unsigned short* __restrict__ nw2T)
{
    if (blockIdx.x < CVT_BLKS) {
        int i = (blockIdx.x * 256 + threadIdx.x) * 8;
        float4 a = *(const float4*)&x[i];
        float4 b = *(const float4*)&x[i + 4];
        s16x8 o;
        o[0] = (short)f2bf(a.x); o[1] = (short)f2bf(a.y);
        o[2] = (short)f2bf(a.z); o[3] = (short)f2bf(a.w);
        o[4] = (short)f2bf(b.x); o[5] = (short)f2bf(b.y);
        o[6] = (short)f2bf(b.z); o[7] = (short)f2bf(b.w);
        *(s16x8*)&xb[i] = o;
    } else {
        int o = (blockIdx.x - CVT_BLKS) * 256 + threadIdx.x;
        if (o < 32768) {
            int n = o >> 8, k = o & 255;
            ew1T[o] = f2bf(ew1[k * FF + n]);
        } else if (o < 49152) {
            int o2 = o - 32768; int n = o2 >> 7, k = o2 & 127;
            ew2T[o2] = f2bf(ew2[k * FF + n]);
        } else if (o < 65536) {
            int o2 = o - 49152; int n = o2 >> 7, k = o2 & 127;
            nw1T[o2] = f2bf(nw1[k * FF + n]);
        } else {
            int o2 = o - 65536; int n = o2 >> 7, k = o2 & 127;
            nw2T[o2] = f2bf(nw2[k * FF + n]);
        }
    }
}

// ---------- nodeY: Y[n][0:128] = x@ew1[0:128];  Y[n][128:256] = x@ew1[128:256]
constexpr int YABS = 136;
constexpr int YNBLK = (NN + 63) / 64;   // 782

__global__ __launch_bounds__(512) void nodeY_kernel(
    const unsigned short* __restrict__ xb,
    const unsigned short* __restrict__ ew1T,
    unsigned short* __restrict__ Y)
{
    __shared__ __align__(16) unsigned short aB[64 * YABS];

    const int t   = threadIdx.x;
    const int w   = t >> 6;
    const int l   = t & 63;
    const int l15 = l & 15;
    const int q8  = l >> 4;
    const int n0  = blockIdx.x * 64;
    const int n   = w * 16 + l15;

    #pragma unroll
    for (int i = 0; i < 2; ++i) {
        int idx = (i * 512 + t) * 8;
        int e = idx >> 7, c = idx & 127;
        s16x8 v = {};
        if (n0 + e < NN) v = *(const s16x8*)(xb + (size_t)(n0 + e) * FF + c);
        *(s16x8*)(aB + e * YABS + c) = v;
    }
    __syncthreads();

    s16x8 ba[4], bb[4];
    #pragma unroll
    for (int ko = 0; ko < 4; ++ko) {
        ba[ko] = *(const s16x8*)(ew1T + (size_t)n * 256 + ko * 32 + q8 * 8);
        bb[ko] = *(const s16x8*)(ew1T + (size_t)n * 256 + 128 + ko * 32 + q8 * 8);
    }

    f32x4 acc1[4] = {}, acc2[4] = {};
    #pragma unroll
    for (int mt = 0; mt < 4; ++mt) {
        const unsigned short* ar = aB + (mt * 16 + l15) * YABS + q8 * 8;
        #pragma unroll
        for (int ko = 0; ko < 4; ++ko) {
            s16x8 a = *(const s16x8*)(ar + ko * 32);
            acc1[mt] = __builtin_amdgcn_mfma_f32_16x16x32_bf16(a, ba[ko], acc1[mt], 0, 0, 0);
            acc2[mt] = __builtin_amdgcn_mfma_f32_16x16x32_bf16(a, bb[ko], acc2[mt], 0, 0, 0);
        }
    }
    #pragma unroll
    for (int mt = 0; mt < 4; ++mt) {
        #pragma unroll
        for (int r = 0; r < 4; ++r) {
            int nn = n0 + mt * 16 + q8 * 4 + r;
            if (nn < NN) {
                Y[(size_t)nn * 256 + n]       = f2bf(acc1[mt][r]);
                Y[(size_t)nn * 256 + 128 + n] = f2bf(acc2[mt][r]);
            }
        }
    }
}

// -------------------- counting sort by row --------------------
__global__ __launch_bounds__(256) void hist_kernel(
    const int* __restrict__ ei, int* __restrict__ cnt)
{
    int e = blockIdx.x * 256 + threadIdx.x;
    if (e < EE) atomicAdd(&cnt[ei[e]], 1);
}

__global__ __launch_bounds__(256) void chunk_sum_kernel(
    const int* __restrict__ cnt, int* __restrict__ chunkSum)
{
    __shared__ int s[256];
    int t = threadIdx.x;
    int idx = blockIdx.x * 256 + t;
    s[t] = (idx < NN) ? cnt[idx] : 0;
    __syncthreads();
    for (int off = 128; off > 0; off >>= 1) {
        if (t < off) s[t] += s[t + off];
        __syncthreads();
    }
    if (t == 0) chunkSum[blockIdx.x] = s[0];
}

__global__ __launch_bounds__(256) void scan_chunks_kernel(
    const int* __restrict__ chunkSum, int* __restrict__ chunkOff)
{
    __shared__ int s[256];
    int t = threadIdx.x;
    int v = (t < NC) ? chunkSum[t] : 0;
    s[t] = v;
    __syncthreads();
    for (int off = 1; off < 256; off <<= 1) {
        int u = (t >= off) ? s[t - off] : 0;
        __syncthreads();
        s[t] += u;
        __syncthreads();
    }
    if (t < NC) chunkOff[t] = s[t] - v;
}

__global__ __launch_bounds__(256) void scan_kernel(
    const int* __restrict__ cnt, const int* __restrict__ chunkOff,
    int* __restrict__ offs)
{
    __shared__ int s[256];
    int t = threadIdx.x;
    int idx = blockIdx.x * 256 + t;
    int v = (idx < NN) ? cnt[idx] : 0;
    s[t] = v;
    __syncthreads();
    for (int off = 1; off < 256; off <<= 1) {
        int u = (t >= off) ? s[t - off] : 0;
        __syncthreads();
        s[t] += u;
        __syncthreads();
    }
    if (idx < NN) {
        offs[idx] = chunkOff[blockIdx.x] + s[t] - v;
    }
}

__global__ __launch_bounds__(256) void scatter_idx_kernel(
    const int* __restrict__ ei, int* __restrict__ offs,
    int2* __restrict__ sPair)
{
    int e = blockIdx.x * 256 + threadIdx.x;
    if (e < EE) {
        int r = ei[e], c = ei[EE + e];
        int p = atomicAdd(&offs[r], 1);
        sPair[p] = make_int2(r, c);
    }
}

// ==================== PASS A: edge MLP -> fused scatter-add ===============
constexpr int EPB    = 64;
constexpr int NTILE  = EE / EPB;    // 12500
constexpr int GRID_A = 2500;        // exactly 5 tiles per block
constexpr int XAS    = 264;         // ya stride: 528 B row (33 quads, odd)
constexpr int H1S    = 136;         // h1 stride: 272 B row (17 quads, odd)
constexpr int MTS    = 72;          // msgT stride (144 B: 16B-aligned rows)

// GEMM1 eliminated (r10, HW-verified). Pos-delta now scattered FROM edgeA:
// wave 7 (lane k = edge k) reduces sPartT[k][*], tanh, and atomically adds
// g*(dx,dy,dz) into posdelta[row]. nodeB's scattered pos-gather is deleted.
// THREE barriers per tile (hazard structure HW-validated r8-r10):
//   looptop: stage ya (Y gather), rowS[bsel], sD[bsel] (dx,dy,dz), dist2S
//   (A) -> prefetch next gather; silu pass (ya -> h1)
//   (B) -> GEMM2; p-shuffle -> sPartT; msgT writes
//   (C) -> wave7: pos-delta scatter (sPartT, sD[bsel], rowS[bsel]);
//          all: segment-reduce (msgT, rowS[bsel]) -> agg atomics
// sD/rowS double-buffered (read after (C); written looptop i+1). sPartT
// reads by wave 7 finish before wave 7 reaches (B)_{i+1} -> safe.
__global__ __launch_bounds__(512, 4) void edgeA_kernel(
    const unsigned short* __restrict__ Yb, const float* __restrict__ pos,
    const int2* __restrict__ sPair,
    const float* __restrict__ ew1, const float* __restrict__ eb1,
    const unsigned short* __restrict__ ew2T, const float* __restrict__ eb2,
    const float* __restrict__ cw,  const float* __restrict__ cb,
    float* __restrict__ agg, float* __restrict__ posdelta)
{
    __shared__ float dist2S[EPB];
    __shared__ int   rowS[2][EPB];
    __shared__ float sD[2][3][EPB];
    __shared__ float sPartT[EPB][8];
    __shared__ __align__(16) unsigned short ya  [EPB * XAS];   // 33792 B
    __shared__ __align__(16) unsigned short h1  [EPB * H1S];   // 17408 B
    __shared__ __align__(16) unsigned short msgT[FF * MTS];    // 18432 B

    const int t   = threadIdx.x;
    const int w   = t >> 6;
    const int l   = t & 63;
    const int l15 = l & 15;
    const int q8  = l >> 4;
    const int n   = w * 16 + l15;

    // XCD-chunked bijective swizzle (sorted tiles -> per-XCD row locality)
    int swz;
    {
        const int qd = GRID_A >> 3, r8 = GRID_A & 7;
        int xcd = blockIdx.x & 7, p8 = blockIdx.x >> 3;
        swz = (xcd < r8 ? xcd * (qd + 1) : r8 * (qd + 1) + (xcd - r8) * qd) + p8;
    }

    s16x8 B2[4];
    #pragma unroll
    for (int ko = 0; ko < 4; ++ko)
        B2[ko] = *(const s16x8*)(ew2T + (size_t)n * 128 + ko * 32 + q8 * 8);
    const float b2   = eb2[n];
    const float cwc  = cw[n];
    const float cb0  = cb[0];

    // silu-pass constants: thread owns 8 columns c8..c8+7 for 2 edges
    const int c8 = (t & 15) * 8;
    const int e2 = (t >> 4) * 2;
    float w256r[8], b1r[8];
    {
        float4 wa = *(const float4*)&ew1[256 * FF + c8];
        float4 wb = *(const float4*)&ew1[256 * FF + c8 + 4];
        w256r[0]=wa.x; w256r[1]=wa.y; w256r[2]=wa.z; w256r[3]=wa.w;
        w256r[4]=wb.x; w256r[5]=wb.y; w256r[6]=wb.z; w256r[7]=wb.w;
        float4 ca = *(const float4*)&eb1[c8];
        float4 cbv = *(const float4*)&eb1[c8 + 4];
        b1r[0]=ca.x; b1r[1]=ca.y; b1r[2]=ca.z; b1r[3]=ca.w;
        b1r[4]=cbv.x; b1r[5]=cbv.y; b1r[6]=cbv.z; b1r[7]=cbv.w;
    }

    const int q    = t & 31;
    const int eB   = t >> 5;
    const int ksel = (q & 15) * 8;
    const bool useRow = (q < 16);
    const int colOff = useRow ? 0 : 128;   // Y1 half for row, Y2 half for col

    int   nidx[4];
    s16x8 ag[4];
    {
        int e0 = swz * EPB;
        #pragma unroll
        for (int i = 0; i < 4; ++i) {
            int2 pr = sPair[e0 + eB + 16 * i];
            nidx[i] = useRow ? pr.x : pr.y;
        }
        #pragma unroll
        for (int i = 0; i < 4; ++i)
            ag[i] = *(const s16x8*)(Yb + (size_t)nidx[i] * 256 + colOff + ksel);
    }

    int bsel = 0;
    for (int tile = swz; tile < NTILE; tile += GRID_A) {
        const int e0 = tile * EPB;

        #pragma unroll
        for (int i = 0; i < 4; ++i)
            *(s16x8*)(ya + (eB + 16 * i) * XAS + q * 8) = ag[i];
        if (t < EPB) {
            int2 pr = sPair[e0 + t];
            int r = pr.x, c = pr.y;
            rowS[bsel][t] = r;
            float dx = pos[r*3+0] - pos[c*3+0];
            float dy = pos[r*3+1] - pos[c*3+1];
            float dz = pos[r*3+2] - pos[c*3+2];
            sD[bsel][0][t] = dx;
            sD[bsel][1][t] = dy;
            sD[bsel][2][t] = dz;
            dist2S[t] = dx*dx + dy*dy + dz*dz;
        }
        __syncthreads();   // (A)

        {
            int tn  = tile + GRID_A;
            int e0n = (tn < NTILE) ? tn * EPB : 0;
            #pragma unroll
            for (int i = 0; i < 4; ++i) {
                int2 pr = sPair[e0n + eB + 16 * i];
                nidx[i] = useRow ? pr.x : pr.y;
            }
            #pragma unroll
            for (int i = 0; i < 4; ++i)
                ag[i] = *(const s16x8*)(Yb + (size_t)nidx[i] * 256 + colOff + ksel);
        }

        // ---- silu pass (replaces GEMM1): h1 = silu(Y1+Y2+d2*w256+b1) ----
        #pragma unroll
        for (int s = 0; s < 2; ++s) {
            int e = e2 + s;
            s16x8 y1 = *(const s16x8*)(ya + e * XAS + c8);
            s16x8 y2 = *(const s16x8*)(ya + e * XAS + 128 + c8);
            float d2 = dist2S[e];
            s16x8 o;
            #pragma unroll
            for (int j = 0; j < 8; ++j) {
                float v = bf2f((unsigned short)y1[j]) + bf2f((unsigned short)y2[j])
                        + d2 * w256r[j] + b1r[j];
                o[j] = (short)f2bf(silu_f(v));
            }
            *(s16x8*)(h1 + e * H1S + c8) = o;
        }
        __syncthreads();   // (B)

        f32x4 acc2[4] = {};
        #pragma unroll
        for (int mt = 0; mt < 4; ++mt) {
            const unsigned short* hr = h1 + (mt * 16 + l15) * H1S + q8 * 8;
            #pragma unroll
            for (int ko = 0; ko < 4; ++ko) {
                s16x8 a = *(const s16x8*)(hr + ko * 32);
                acc2[mt] = __builtin_amdgcn_mfma_f32_16x16x32_bf16(a, B2[ko], acc2[mt], 0, 0, 0);
            }
        }

        // p = msg.cw partial sums via shuffles (verified r7-r10);
        // msg -> msgT[n][e] transposed: one ds_write_b64 per mt (r8-r10).
        #pragma unroll
        for (int mt = 0; mt < 4; ++mt) {
            u16x4 o;
            #pragma unroll
            for (int r = 0; r < 4; ++r) {
                float m = acc2[mt][r] + b2;
                o[r] = f2bf(m);
                float p = m * cwc;
                p += __shfl_xor(p, 1);
                p += __shfl_xor(p, 2);
                p += __shfl_xor(p, 4);
                p += __shfl_xor(p, 8);
                if (l15 == 0) sPartT[mt * 16 + q8 * 4 + r][w] = p;
            }
            *(u16x4*)(msgT + n * MTS + mt * 16 + q8 * 4) = o;
        }
        __syncthreads();   // (C)

        // ---- pos-delta scatter: wave 7, lane k = edge k ----
        if (t >= 448) {
            int k = t - 448;
            const float* pp = &sPartT[k][0];
            float4 pa = *(const float4*)pp;
            float4 pb = *(const float4*)(pp + 4);
            float p = ((pa.x + pa.y) + (pa.z + pa.w))
                    + ((pb.x + pb.y) + (pb.z + pb.w));
            float g = tanhf(p + cb0);
            int r = rowS[bsel][k];
            atomicAdd(&posdelta[r * 3 + 0], g * sD[bsel][0][k]);
            atomicAdd(&posdelta[r * 3 + 1], g * sD[bsel][1][k]);
            atomicAdd(&posdelta[r * 3 + 2], g * sD[bsel][2][k]);
        }

        // ---- fused segment-reduce + scatter-add into agg ----
        {
            int c    = t & 127;
            int s    = t >> 7;
            int base = s * 16;
            const unsigned short* mr = msgT + c * MTS + base;
            s16x8 v0 = *(const s16x8*)(mr);
            s16x8 v1 = *(const s16x8*)(mr + 8);
            float a  = 0.f;
            int cur  = rowS[bsel][base];
            #pragma unroll
            for (int k = 0; k < 16; ++k) {
                int r = rowS[bsel][base + k];
                if (r != cur) {
                    atomicAdd(&agg[(size_t)cur * FF + c], a);
                    a = 0.f; cur = r;
                }
                unsigned short mv = (k < 8) ? (unsigned short)v0[k]
                                            : (unsigned short)v1[k - 8];
                a += bf2f(mv);
            }
            atomicAdd(&agg[(size_t)cur * FF + c], a);
        }
        bsel ^= 1;
    }
}

// ==================== PASS B: agg read + MFMA node MLP + LN + pos add =====
constexpr int NPB  = 64;
constexpr int ABS  = 136;                      // bf16 LDS row stride
constexpr int NBLK = (NN + NPB - 1) / NPB;     // 782 (last block: 16 valid)

__global__ __launch_bounds__(512) void nodeB_kernel(
    const float* __restrict__ x, const float* __restrict__ pos,
    const float* __restrict__ agg, const float* __restrict__ posdelta,
    const unsigned short* __restrict__ nw1T, const float* __restrict__ nb1,
    const unsigned short* __restrict__ nw2T, const float* __restrict__ nb2,
    const float* __restrict__ gamma, const float* __restrict__ beta,
    float* __restrict__ xout, float* __restrict__ posout)
{
    __shared__ __align__(16) unsigned short aB [NPB * ABS];   // 17408 B
    __shared__ __align__(16) unsigned short h1B[NPB * ABS];   // 17408 B
    __shared__ float sRedS[8][NPB];
    __shared__ float sRedQ[8][NPB];

    const int t   = threadIdx.x;
    const int w   = t >> 6;          // 0..7
    const int l   = t & 63;
    const int l15 = l & 15;
    const int q8  = l >> 4;          // 0..3
    const int n0  = blockIdx.x * NPB;
    const int n   = w * 16 + l15;    // this wave's output column

    // ---- load agg rows (f32) -> aB (bf16): 8192 floats, 16 per thread ----
    #pragma unroll
    for (int i = 0; i < 4; ++i) {
        int idx = (i * 512 + t) * 4;
        int e = idx >> 7, c = idx & 127;
        u16x4 o;
        if (n0 + e < NN) {
            float4 v = *(const float4*)&agg[(size_t)(n0 + e) * FF + c];
            o[0] = f2bf(v.x); o[1] = f2bf(v.y); o[2] = f2bf(v.z); o[3] = f2bf(v.w);
        } else {
            o[0] = 0; o[1] = 0; o[2] = 0; o[3] = 0;
        }
        *(u16x4*)(aB + e * ABS + c) = o;
    }

    // ---- pos update: coalesced add of precomputed delta ----
    if (t < NPB * 3) {
        int i = n0 * 3 + t;
        if (i < NN * 3) posout[i] = pos[i] + posdelta[i];
    }
    __syncthreads();

    // ---- GEMM1 (64 nodes x 128 cols, K=128): wave w -> 16 cols ----
    f32x4 acc[4] = {};
    {
        s16x8 bw[4];
        #pragma unroll
        for (int ko = 0; ko < 4; ++ko)
            bw[ko] = *(const s16x8*)(nw1T + (size_t)n * 128 + ko * 32 + q8 * 8);
        #pragma unroll
        for (int mt = 0; mt < 4; ++mt) {
            const unsigned short* ar = aB + (mt * 16 + l15) * ABS + q8 * 8;
            #pragma unroll
            for (int ko = 0; ko < 4; ++ko) {
                s16x8 a = *(const s16x8*)(ar + ko * 32);
                acc[mt] = __builtin_amdgcn_mfma_f32_16x16x32_bf16(a, bw[ko], acc[mt], 0, 0, 0);
            }
        }
    }
    {
        float bb = nb1[n];
        #pragma unroll
        for (int mt = 0; mt < 4; ++mt) {
            #pragma unroll
            for (int r = 0; r < 4; ++r) {
                int e = mt * 16 + q8 * 4 + r;
                h1B[e * ABS + n] = f2bf(silu_f(acc[mt][r] + bb));
            }
        }
    }
    __syncthreads();

    // ---- GEMM2 (K=128) ----
    f32x4 acc2[4] = {};
    {
        s16x8 bw[4];
        #pragma unroll
        for (int ko = 0; ko < 4; ++ko)
            bw[ko] = *(const s16x8*)(nw2T + (size_t)n * 128 + ko * 32 + q8 * 8);
        #pragma unroll
        for (int mt = 0; mt < 4; ++mt) {
            const unsigned short* hr = h1B + (mt * 16 + l15) * ABS + q8 * 8;
            #pragma unroll
            for (int ko = 0; ko < 4; ++ko) {
                s16x8 a = *(const s16x8*)(hr + ko * 32);
                acc2[mt] = __builtin_amdgcn_mfma_f32_16x16x32_bf16(a, bw[ko], acc2[mt], 0, 0, 0);
            }
        }
    }

    // ---- residual + LN ----
    float pre[4][4];
    {
        float bb = nb2[n];
        #pragma unroll
        for (int mt = 0; mt < 4; ++mt) {
            #pragma unroll
            for (int r = 0; r < 4; ++r) {
                int e  = mt * 16 + q8 * 4 + r;
                int nn = n0 + e;
                float xv = (nn < NN) ? x[(size_t)nn * FF + n] : 0.f;
                pre[mt][r] = xv + acc2[mt][r] + bb;
            }
        }
    }
    #pragma unroll
    for (int mt = 0; mt < 4; ++mt) {
        #pragma unroll
        for (int r = 0; r < 4; ++r) {
            float s = pre[mt][r], sq = pre[mt][r] * pre[mt][r];
            s += __shfl_xor(s, 1);  sq += __shfl_xor(sq, 1);
            s += __shfl_xor(s, 2);  sq += __shfl_xor(sq, 2);
            s += __shfl_xor(s, 4);  sq += __shfl_xor(sq, 4);
            s += __shfl_xor(s, 8);  sq += __shfl_xor(sq, 8);
            if (l15 == 0) {
                int e = mt * 16 + q8 * 4 + r;
                sRedS[w][e] = s;
                sRedQ[w][e] = sq;
            }
        }
    }
    __syncthreads();

    {
        float g = gamma[n], bt = beta[n];
        #pragma unroll
        for (int mt = 0; mt < 4; ++mt) {
            #pragma unroll
            for (int r = 0; r < 4; ++r) {
                int e  = mt * 16 + q8 * 4 + r;
                int nn = n0 + e;
                if (nn < NN) {
                    float S = 0.f, Q = 0.f;
                    #pragma unroll
                    for (int ww = 0; ww < 8; ++ww) { S += sRedS[ww][e]; Q += sRedQ[ww][e]; }
                    float mean = S * (1.f / FF);
                    float var  = Q * (1.f / FF) - mean * mean;
                    xout[(size_t)nn * FF + n] =
                        g * (pre[mt][r] - mean) * rsqrtf(var + LN_EPS) + bt;
                }
            }
        }
    }
}

// -------------------- launcher --------------------
extern "C" void kernel_launch(void* const* d_in, const int* in_sizes, int n_in,
                              void* d_out, int out_size, void* d_ws, size_t ws_size,
                              hipStream_t stream) {
    const float* x    = (const float*)d_in[0];
    const float* pos  = (const float*)d_in[1];
    const int*   ei   = (const int*)  d_in[2];
    const float* ew1  = (const float*)d_in[3];
    const float* eb1  = (const float*)d_in[4];
    const float* ew2  = (const float*)d_in[5];
    const float* eb2  = (const float*)d_in[6];
    const float* nw1  = (const float*)d_in[7];
    const float* nb1  = (const float*)d_in[8];
    const float* nw2  = (const float*)d_in[9];
    const float* nb2  = (const float*)d_in[10];
    const float* cw   = (const float*)d_in[11];
    const float* cb   = (const float*)d_in[12];
    const float* gam  = (const float*)d_in[13];
    const float* bet  = (const float*)d_in[14];

    float* out    = (float*)d_out;
    float* xout   = out;
    float* posout = out + (size_t)NN * FF;

    auto align256 = [](size_t v) { return (v + 255) & ~(size_t)255; };
    char* ws = (char*)d_ws;

    size_t CNT_B   = align256((size_t)NN * 4);
    size_t OFFS_B  = align256((size_t)NN * 4);
    size_t CHNK_B  = align256((size_t)NC * 4 * 2);
    size_t SPAIR_B = align256((size_t)EE * 8);
    size_t XB_B    = align256((size_t)NN * FF * 2);
    size_t EW1T_B  = align256((size_t)128 * 256 * 2);
    size_t WT_B    = align256((size_t)128 * 128 * 2);
    size_t Y_B     = align256((size_t)NN * 256 * 2);  // 25.6 MB bf16
    size_t AGG_B   = align256((size_t)NN * FF * 4);   // 25.6 MB f32
    size_t PD_B    = align256((size_t)NN * 3 * 4);    // 600 KB f32

    size_t o = 0;
    int* cnt       = (int*)(ws + o);  o += CNT_B;    // zeroed
    int* offs      = (int*)(ws + o);  o += OFFS_B;
    int* chunkSum  = (int*)(ws + o);
    int* chunkOff  = chunkSum + NC;   o += CHNK_B;
    int2* sPair    = (int2*)(ws + o); o += SPAIR_B;
    unsigned short* xb   = (unsigned short*)(ws + o);  o += XB_B;
    unsigned short* ew1T = (unsigned short*)(ws + o);  o += EW1T_B;
    unsigned short* ew2T = (unsigned short*)(ws + o);  o += WT_B;
    unsigned short* nw1T = (unsigned short*)(ws + o);  o += WT_B;
    unsigned short* nw2T = (unsigned short*)(ws + o);  o += WT_B;
    unsigned short* Yb   = (unsigned short*)(ws + o);  o += Y_B;
    float*          agg  = (float*)(ws + o);           o += AGG_B;
    float*          posd = (float*)(ws + o);           o += PD_B;

    hipMemsetAsync(cnt, 0, CNT_B, stream);
    hipMemsetAsync(agg, 0, (size_t)NN * FF * 4, stream);
    hipMemsetAsync(posd, 0, (size_t)NN * 3 * 4, stream);

    prep_kernel<<<CVT_BLKS + TRW_BLKS, 256, 0, stream>>>(
        x, xb, ew1, ew2, nw1, nw2, ew1T, ew2T, nw1T, nw2T);

    nodeY_kernel<<<YNBLK, 512, 0, stream>>>(xb, ew1T, Yb);

    hist_kernel<<<(EE + 255) / 256, 256, 0, stream>>>(ei, cnt);
    chunk_sum_kernel<<<NC, 256, 0, stream>>>(cnt, chunkSum);
    scan_chunks_kernel<<<1, 256, 0, stream>>>(chunkSum, chunkOff);
    scan_kernel<<<NC, 256, 0, stream>>>(cnt, chunkOff, offs);
    scatter_idx_kernel<<<(EE + 255) / 256, 256, 0, stream>>>(ei, offs, sPair);

    edgeA_kernel<<<GRID_A, 512, 0, stream>>>(
        Yb, pos, sPair, ew1, eb1, ew2T, eb2, cw, cb, agg, posd);

    nodeB_kernel<<<NBLK, 512, 0, stream>>>(
        x, pos, agg, posd,
        nw1T, nb1, nw2T, nb2, gam, bet, xout, posout);
}

// Round 12
// 478.561 us; speedup vs baseline: 1.2486x; 1.2486x over previous
//
#include <hip/hip_runtime.h>
#include <math.h>

#define NN 50000
#define EE 800000
#define FF 128

constexpr float LN_EPS = 1e-5f;
constexpr int NC = (NN + 255) / 256;   // 196 scan chunks

typedef float  f32x4  __attribute__((ext_vector_type(4)));
typedef short  s16x8  __attribute__((ext_vector_type(8)));
typedef unsigned short u16x4 __attribute__((ext_vector_type(4)));

__device__ __forceinline__ float silu_f(float v) {
    return v / (1.f + __expf(-v));
}

__device__ __forceinline__ unsigned short f2bf(float f) {
    union { float f; unsigned u; } cv; cv.f = f;
    unsigned u = cv.u;
    u += 0x7fffu + ((u >> 16) & 1u);   // round-to-nearest-even
    return (unsigned short)(u >> 16);
}

__device__ __forceinline__ float bf2f(unsigned short u) {
    union { unsigned u; float f; } cv; cv.u = ((unsigned)u) << 16;
    return cv.f;
}

// ---------- fused prep: x->bf16, weight transposes, AND row histogram -----
constexpr int CVT_BLKS  = (NN * FF / 8) / 256;       // 3125
constexpr int TRW_BLKS  = (32768 + 3 * 16384) / 256; // 320
constexpr int HIST_BLKS = (EE + 255) / 256;          // 3125

__global__ __launch_bounds__(256) void prep_kernel(
    const float* __restrict__ x, unsigned short* __restrict__ xb,
    const float* __restrict__ ew1, const float* __restrict__ ew2,
    const float* __restrict__ nw1, const float* __restrict__ nw2,
    unsigned short* __restrict__ ew1T, unsigned short* __restrict__ ew2T,
    unsigned short* __restrict__ nw1T, unsigned short* __restrict__ nw2T,
    const int* __restrict__ ei, int* __restrict__ cnt)
{
    if (blockIdx.x < CVT_BLKS) {
        int i = (blockIdx.x * 256 + threadIdx.x) * 8;
        float4 a = *(const float4*)&x[i];
        float4 b = *(const float4*)&x[i + 4];
        s16x8 o;
        o[0] = (short)f2bf(a.x); o[1] = (short)f2bf(a.y);
        o[2] = (short)f2bf(a.z); o[3] = (short)f2bf(a.w);
        o[4] = (short)f2bf(b.x); o[5] = (short)f2bf(b.y);
        o[6] = (short)f2bf(b.z); o[7] = (short)f2bf(b.w);
        *(s16x8*)&xb[i] = o;
    } else if (blockIdx.x < CVT_BLKS + TRW_BLKS) {
        int o = (blockIdx.x - CVT_BLKS) * 256 + threadIdx.x;
        if (o < 32768) {
            int n = o >> 8, k = o & 255;
            ew1T[o] = f2bf(ew1[k * FF + n]);
        } else if (o < 49152) {
            int o2 = o - 32768; int n = o2 >> 7, k = o2 & 127;
            ew2T[o2] = f2bf(ew2[k * FF + n]);
        } else if (o < 65536) {
            int o2 = o - 49152; int n = o2 >> 7, k = o2 & 127;
            nw1T[o2] = f2bf(nw1[k * FF + n]);
        } else {
            int o2 = o - 65536; int n = o2 >> 7, k = o2 & 127;
            nw2T[o2] = f2bf(nw2[k * FF + n]);
        }
    } else {
        int e = (blockIdx.x - CVT_BLKS - TRW_BLKS) * 256 + threadIdx.x;
        if (e < EE) atomicAdd(&cnt[ei[e]], 1);
    }
}

// ---------- nodeY: Y[n][0:128] = x@ew1[0:128];  Y[n][128:256] = x@ew1[128:256]
constexpr int YABS = 136;
constexpr int YNBLK = (NN + 63) / 64;   // 782

__global__ __launch_bounds__(512) void nodeY_kernel(
    const unsigned short* __restrict__ xb,
    const unsigned short* __restrict__ ew1T,
    unsigned short* __restrict__ Y)
{
    __shared__ __align__(16) unsigned short aB[64 * YABS];

    const int t   = threadIdx.x;
    const int w   = t >> 6;
    const int l   = t & 63;
    const int l15 = l & 15;
    const int q8  = l >> 4;
    const int n0  = blockIdx.x * 64;
    const int n   = w * 16 + l15;

    #pragma unroll
    for (int i = 0; i < 2; ++i) {
        int idx = (i * 512 + t) * 8;
        int e = idx >> 7, c = idx & 127;
        s16x8 v = {};
        if (n0 + e < NN) v = *(const s16x8*)(xb + (size_t)(n0 + e) * FF + c);
        *(s16x8*)(aB + e * YABS + c) = v;
    }
    __syncthreads();

    s16x8 ba[4], bb[4];
    #pragma unroll
    for (int ko = 0; ko < 4; ++ko) {
        ba[ko] = *(const s16x8*)(ew1T + (size_t)n * 256 + ko * 32 + q8 * 8);
        bb[ko] = *(const s16x8*)(ew1T + (size_t)n * 256 + 128 + ko * 32 + q8 * 8);
    }

    f32x4 acc1[4] = {}, acc2[4] = {};
    #pragma unroll
    for (int mt = 0; mt < 4; ++mt) {
        const unsigned short* ar = aB + (mt * 16 + l15) * YABS + q8 * 8;
        #pragma unroll
        for (int ko = 0; ko < 4; ++ko) {
            s16x8 a = *(const s16x8*)(ar + ko * 32);
            acc1[mt] = __builtin_amdgcn_mfma_f32_16x16x32_bf16(a, ba[ko], acc1[mt], 0, 0, 0);
            acc2[mt] = __builtin_amdgcn_mfma_f32_16x16x32_bf16(a, bb[ko], acc2[mt], 0, 0, 0);
        }
    }
    #pragma unroll
    for (int mt = 0; mt < 4; ++mt) {
        #pragma unroll
        for (int r = 0; r < 4; ++r) {
            int nn = n0 + mt * 16 + q8 * 4 + r;
            if (nn < NN) {
                Y[(size_t)nn * 256 + n]       = f2bf(acc1[mt][r]);
                Y[(size_t)nn * 256 + 128 + n] = f2bf(acc2[mt][r]);
            }
        }
    }
}

// -------------------- counting sort by row --------------------
__global__ __launch_bounds__(256) void chunk_sum_kernel(
    const int* __restrict__ cnt, int* __restrict__ chunkSum)
{
    __shared__ int s[256];
    int t = threadIdx.x;
    int idx = blockIdx.x * 256 + t;
    s[t] = (idx < NN) ? cnt[idx] : 0;
    __syncthreads();
    for (int off = 128; off > 0; off >>= 1) {
        if (t < off) s[t] += s[t + off];
        __syncthreads();
    }
    if (t == 0) chunkSum[blockIdx.x] = s[0];
}

__global__ __launch_bounds__(256) void scan_chunks_kernel(
    const int* __restrict__ chunkSum, int* __restrict__ chunkOff)
{
    __shared__ int s[256];
    int t = threadIdx.x;
    int v = (t < NC) ? chunkSum[t] : 0;
    s[t] = v;
    __syncthreads();
    for (int off = 1; off < 256; off <<= 1) {
        int u = (t >= off) ? s[t - off] : 0;
        __syncthreads();
        s[t] += u;
        __syncthreads();
    }
    if (t < NC) chunkOff[t] = s[t] - v;
}

__global__ __launch_bounds__(256) void scan_kernel(
    const int* __restrict__ cnt, const int* __restrict__ chunkOff,
    int* __restrict__ offs, int* __restrict__ rowStart)
{
    __shared__ int s[256];
    int t = threadIdx.x;
    int idx = blockIdx.x * 256 + t;
    int v = (idx < NN) ? cnt[idx] : 0;
    s[t] = v;
    __syncthreads();
    for (int off = 1; off < 256; off <<= 1) {
        int u = (t >= off) ? s[t - off] : 0;
        __syncthreads();
        s[t] += u;
        __syncthreads();
    }
    if (idx < NN) {
        int st = chunkOff[blockIdx.x] + s[t] - v;
        offs[idx] = st;
        rowStart[idx] = st;
    }
}

__global__ __launch_bounds__(256) void scatter_idx_kernel(
    const int* __restrict__ ei, int* __restrict__ offs,
    int2* __restrict__ sPair)
{
    int e = blockIdx.x * 256 + threadIdx.x;
    if (e < EE) {
        int r = ei[e], c = ei[EE + e];
        int p = atomicAdd(&offs[r], 1);
        sPair[p] = make_int2(r, c);
    }
}

// ==================== PASS A: edge MLP -> fused scatter-add ===============
constexpr int EPB    = 64;
constexpr int NTILE  = EE / EPB;    // 12500
constexpr int GRID_A = 2500;        // exactly 5 tiles per block
constexpr int XAS    = 264;         // ya stride: 528 B row (33 quads, odd)
constexpr int H1S    = 136;         // h1 stride: 272 B row (17 quads, odd)
constexpr int MTS    = 72;          // msgT stride (144 B: 16B-aligned rows)

// r10 structure (HW-verified, 465.6us) + msgT 16B-block XOR swizzle:
// block index b = byte_ofs>>4 within a row is XORed with (row&7) on BOTH
// write (two 8B stores per mt) and read (two independent 16B reads) --
// spreads the segment-reduce's ds_read_b128 from 8 banks to all 32.
// THREE barriers per tile:
//   looptop: stage ya (Y gather), rowS[bsel], dist2S
//   (A) -> prefetch next gather; silu pass (ya -> h1)
//   (B) -> GEMM2; p-shuffle -> sPartT; msgT writes (swizzled)
//   (C) -> tanh (sPartT) -> sSg; segment-reduce (msgT, rowS[bsel]) -> atomics
__global__ __launch_bounds__(512, 4) void edgeA_kernel(
    const unsigned short* __restrict__ Yb, const float* __restrict__ pos,
    const int2* __restrict__ sPair,
    const float* __restrict__ ew1, const float* __restrict__ eb1,
    const unsigned short* __restrict__ ew2T, const float* __restrict__ eb2,
    const float* __restrict__ cw,  const float* __restrict__ cb,
    float* __restrict__ agg, float* __restrict__ sSg)
{
    __shared__ float dist2S[EPB];
    __shared__ int   rowS[2][EPB];
    __shared__ float sPartT[EPB][8];
    __shared__ __align__(16) unsigned short ya  [EPB * XAS];   // 33792 B
    __shared__ __align__(16) unsigned short h1  [EPB * H1S];   // 17408 B
    __shared__ __align__(16) unsigned short msgT[FF * MTS];    // 18432 B

    const int t   = threadIdx.x;
    const int w   = t >> 6;
    const int l   = t & 63;
    const int l15 = l & 15;
    const int q8  = l >> 4;
    const int n   = w * 16 + l15;

    // XCD-chunked bijective swizzle (sorted tiles -> per-XCD row locality)
    int swz;
    {
        const int qd = GRID_A >> 3, r8 = GRID_A & 7;
        int xcd = blockIdx.x & 7, p8 = blockIdx.x >> 3;
        swz = (xcd < r8 ? xcd * (qd + 1) : r8 * (qd + 1) + (xcd - r8) * qd) + p8;
    }

    s16x8 B2[4];
    #pragma unroll
    for (int ko = 0; ko < 4; ++ko)
        B2[ko] = *(const s16x8*)(ew2T + (size_t)n * 128 + ko * 32 + q8 * 8);
    const float b2   = eb2[n];
    const float cwc  = cw[n];
    const float cb0  = cb[0];

    // silu-pass constants: thread owns 8 columns c8..c8+7 for 2 edges
    const int c8 = (t & 15) * 8;
    const int e2 = (t >> 4) * 2;
    float w256r[8], b1r[8];
    {
        float4 wa = *(const float4*)&ew1[256 * FF + c8];
        float4 wb = *(const float4*)&ew1[256 * FF + c8 + 4];
        w256r[0]=wa.x; w256r[1]=wa.y; w256r[2]=wa.z; w256r[3]=wa.w;
        w256r[4]=wb.x; w256r[5]=wb.y; w256r[6]=wb.z; w256r[7]=wb.w;
        float4 ca = *(const float4*)&eb1[c8];
        float4 cbv = *(const float4*)&eb1[c8 + 4];
        b1r[0]=ca.x; b1r[1]=ca.y; b1r[2]=ca.z; b1r[3]=ca.w;
        b1r[4]=cbv.x; b1r[5]=cbv.y; b1r[6]=cbv.z; b1r[7]=cbv.w;
    }

    const int q    = t & 31;
    const int eB   = t >> 5;
    const int ksel = (q & 15) * 8;
    const bool useRow = (q < 16);
    const int colOff = useRow ? 0 : 128;   // Y1 half for row, Y2 half for col

    int   nidx[4];
    s16x8 ag[4];
    {
        int e0 = swz * EPB;
        #pragma unroll
        for (int i = 0; i < 4; ++i) {
            int2 pr = sPair[e0 + eB + 16 * i];
            nidx[i] = useRow ? pr.x : pr.y;
        }
        #pragma unroll
        for (int i = 0; i < 4; ++i)
            ag[i] = *(const s16x8*)(Yb + (size_t)nidx[i] * 256 + colOff + ksel);
    }

    int bsel = 0;
    for (int tile = swz; tile < NTILE; tile += GRID_A) {
        const int e0 = tile * EPB;

        #pragma unroll
        for (int i = 0; i < 4; ++i)
            *(s16x8*)(ya + (eB + 16 * i) * XAS + q * 8) = ag[i];
        if (t < EPB) {
            int2 pr = sPair[e0 + t];
            int r = pr.x, c = pr.y;
            rowS[bsel][t] = r;
            float dx = pos[r*3+0] - pos[c*3+0];
            float dy = pos[r*3+1] - pos[c*3+1];
            float dz = pos[r*3+2] - pos[c*3+2];
            dist2S[t] = dx*dx + dy*dy + dz*dz;
        }
        __syncthreads();   // (A)

        {
            int tn  = tile + GRID_A;
            int e0n = (tn < NTILE) ? tn * EPB : 0;
            #pragma unroll
            for (int i = 0; i < 4; ++i) {
                int2 pr = sPair[e0n + eB + 16 * i];
                nidx[i] = useRow ? pr.x : pr.y;
            }
            #pragma unroll
            for (int i = 0; i < 4; ++i)
                ag[i] = *(const s16x8*)(Yb + (size_t)nidx[i] * 256 + colOff + ksel);
        }

        // ---- silu pass (replaces GEMM1): h1 = silu(Y1+Y2+d2*w256+b1) ----
        #pragma unroll
        for (int s = 0; s < 2; ++s) {
            int e = e2 + s;
            s16x8 y1 = *(const s16x8*)(ya + e * XAS + c8);
            s16x8 y2 = *(const s16x8*)(ya + e * XAS + 128 + c8);
            float d2 = dist2S[e];
            s16x8 o;
            #pragma unroll
            for (int j = 0; j < 8; ++j) {
                float v = bf2f((unsigned short)y1[j]) + bf2f((unsigned short)y2[j])
                        + d2 * w256r[j] + b1r[j];
                o[j] = (short)f2bf(silu_f(v));
            }
            *(s16x8*)(h1 + e * H1S + c8) = o;
        }
        __syncthreads();   // (B)

        f32x4 acc2[4] = {};
        #pragma unroll
        for (int mt = 0; mt < 4; ++mt) {
            const unsigned short* hr = h1 + (mt * 16 + l15) * H1S + q8 * 8;
            #pragma unroll
            for (int ko = 0; ko < 4; ++ko) {
                s16x8 a = *(const s16x8*)(hr + ko * 32);
                acc2[mt] = __builtin_amdgcn_mfma_f32_16x16x32_bf16(a, B2[ko], acc2[mt], 0, 0, 0);
            }
        }

        // p = msg.cw partial sums via shuffles (verified r7-r10);
        // msg -> msgT[n][e] transposed, 16B-block XOR-swizzled by (n&7).
        #pragma unroll
        for (int mt = 0; mt < 4; ++mt) {
            u16x4 o;
            #pragma unroll
            for (int r = 0; r < 4; ++r) {
                float m = acc2[mt][r] + b2;
                o[r] = f2bf(m);
                float p = m * cwc;
                p += __shfl_xor(p, 1);
                p += __shfl_xor(p, 2);
                p += __shfl_xor(p, 4);
                p += __shfl_xor(p, 8);
                if (l15 == 0) sPartT[mt * 16 + q8 * 4 + r][w] = p;
            }
            int b  = mt * 2 + (q8 >> 1);        // 16B block within row
            int bs = b ^ (n & 7);               // swizzled block
            *(u16x4*)(msgT + n * MTS + bs * 8 + (q8 & 1) * 4) = o;
        }
        __syncthreads();   // (C)

        // ---- tanh(coord scale), all 512 threads ----
        {
            int e  = t >> 3;
            int ww = t & 7;
            float p = sPartT[e][ww];
            p += __shfl_xor(p, 1);
            p += __shfl_xor(p, 2);
            p += __shfl_xor(p, 4);
            if (ww == 0) sSg[e0 + e] = tanhf(p + cb0);
        }

        // ---- fused segment-reduce + scatter-add into agg ----
        // thread t: column c = t&127, edge-quarter s = t>>7 (16 edges).
        // Two 16B reads with per-block inverse swizzle (same XOR).
        {
            int c    = t & 127;
            int s    = t >> 7;
            int base = s * 16;
            int b0 = (2 * s)     ^ (c & 7);
            int b1 = (2 * s + 1) ^ (c & 7);
            s16x8 v0 = *(const s16x8*)(msgT + c * MTS + b0 * 8);
            s16x8 v1 = *(const s16x8*)(msgT + c * MTS + b1 * 8);
            float a  = 0.f;
            int cur  = rowS[bsel][base];
            #pragma unroll
            for (int k = 0; k < 16; ++k) {
                int r = rowS[bsel][base + k];
                if (r != cur) {
                    atomicAdd(&agg[(size_t)cur * FF + c], a);
                    a = 0.f; cur = r;
                }
                unsigned short mv = (k < 8) ? (unsigned short)v0[k]
                                            : (unsigned short)v1[k - 8];
                a += bf2f(mv);
            }
            atomicAdd(&agg[(size_t)cur * FF + c], a);
        }
        bsel ^= 1;
    }
}

// ==================== PASS B: agg read + MFMA node MLP + LN + pos =========
constexpr int NPB  = 64;
constexpr int ABS  = 136;                      // bf16 LDS row stride
constexpr int NBLK = (NN + NPB - 1) / NPB;     // 782 (last block: 16 valid)

__global__ __launch_bounds__(512) void nodeB_kernel(
    const float* __restrict__ x, const float* __restrict__ pos,
    const float* __restrict__ agg, const float* __restrict__ sSg,
    const int2* __restrict__ sPair, const int* __restrict__ rowStart,
    const unsigned short* __restrict__ nw1T, const float* __restrict__ nb1,
    const unsigned short* __restrict__ nw2T, const float* __restrict__ nb2,
    const float* __restrict__ gamma, const float* __restrict__ beta,
    float* __restrict__ xout, float* __restrict__ posout)
{
    __shared__ __align__(16) unsigned short aB [NPB * ABS];   // 17408 B
    __shared__ __align__(16) unsigned short h1B[NPB * ABS];   // 17408 B
    __shared__ float sRedS[8][NPB];
    __shared__ float sRedQ[8][NPB];

    const int t   = threadIdx.x;
    const int w   = t >> 6;          // 0..7
    const int l   = t & 63;
    const int l15 = l & 15;
    const int q8  = l >> 4;          // 0..3
    const int n0  = blockIdx.x * NPB;
    const int n   = w * 16 + l15;    // this wave's output column

    // ---- load agg rows (f32) -> aB (bf16): 8192 floats, 16 per thread ----
    #pragma unroll
    for (int i = 0; i < 4; ++i) {
        int idx = (i * 512 + t) * 4;
        int e = idx >> 7, c = idx & 127;
        u16x4 o;
        if (n0 + e < NN) {
            float4 v = *(const float4*)&agg[(size_t)(n0 + e) * FF + c];
            o[0] = f2bf(v.x); o[1] = f2bf(v.y); o[2] = f2bf(v.z); o[3] = f2bf(v.w);
        } else {
            o[0] = 0; o[1] = 0; o[2] = 0; o[3] = 0;
        }
        *(u16x4*)(aB + e * ABS + c) = o;
    }

    // ---- pos update: 8 chunks per node, all 512 threads ----
    {
        int e  = t >> 3;             // 0..63
        int ch = t & 7;              // 0..7
        int nn = n0 + e;
        bool ok = nn < NN;
        int p0 = ok ? rowStart[nn] : 0;
        int p1 = ok ? ((nn == NN - 1) ? EE : rowStart[nn + 1]) : 0;
        float px = ok ? pos[nn*3+0] : 0.f;
        float py = ok ? pos[nn*3+1] : 0.f;
        float pz = ok ? pos[nn*3+2] : 0.f;
        float sx = 0.f, sy = 0.f, sz = 0.f;
        for (int p = p0 + ch; p < p1; p += 8) {
            int c = sPair[p].y;
            float g = sSg[p];
            sx += g * (px - pos[c*3+0]);
            sy += g * (py - pos[c*3+1]);
            sz += g * (pz - pos[c*3+2]);
        }
        #pragma unroll
        for (int off = 1; off < 8; off <<= 1) {
            sx += __shfl_xor(sx, off);
            sy += __shfl_xor(sy, off);
            sz += __shfl_xor(sz, off);
        }
        if (ch == 0 && ok) {
            posout[nn*3+0] = px + sx;
            posout[nn*3+1] = py + sy;
            posout[nn*3+2] = pz + sz;
        }
    }
    __syncthreads();

    // ---- GEMM1 (64 nodes x 128 cols, K=128): wave w -> 16 cols ----
    f32x4 acc[4] = {};
    {
        s16x8 bw[4];
        #pragma unroll
        for (int ko = 0; ko < 4; ++ko)
            bw[ko] = *(const s16x8*)(nw1T + (size_t)n * 128 + ko * 32 + q8 * 8);
        #pragma unroll
        for (int mt = 0; mt < 4; ++mt) {
            const unsigned short* ar = aB + (mt * 16 + l15) * ABS + q8 * 8;
            #pragma unroll
            for (int ko = 0; ko < 4; ++ko) {
                s16x8 a = *(const s16x8*)(ar + ko * 32);
                acc[mt] = __builtin_amdgcn_mfma_f32_16x16x32_bf16(a, bw[ko], acc[mt], 0, 0, 0);
            }
        }
    }
    {
        float bb = nb1[n];
        #pragma unroll
        for (int mt = 0; mt < 4; ++mt) {
            #pragma unroll
            for (int r = 0; r < 4; ++r) {
                int e = mt * 16 + q8 * 4 + r;
                h1B[e * ABS + n] = f2bf(silu_f(acc[mt][r] + bb));
            }
        }
    }
    __syncthreads();

    // ---- GEMM2 (K=128) ----
    f32x4 acc2[4] = {};
    {
        s16x8 bw[4];
        #pragma unroll
        for (int ko = 0; ko < 4; ++ko)
            bw[ko] = *(const s16x8*)(nw2T + (size_t)n * 128 + ko * 32 + q8 * 8);
        #pragma unroll
        for (int mt = 0; mt < 4; ++mt) {
            const unsigned short* hr = h1B + (mt * 16 + l15) * ABS + q8 * 8;
            #pragma unroll
            for (int ko = 0; ko < 4; ++ko) {
                s16x8 a = *(const s16x8*)(hr + ko * 32);
                acc2[mt] = __builtin_amdgcn_mfma_f32_16x16x32_bf16(a, bw[ko], acc2[mt], 0, 0, 0);
            }
        }
    }

    // ---- residual + LN ----
    float pre[4][4];
    {
        float bb = nb2[n];
        #pragma unroll
        for (int mt = 0; mt < 4; ++mt) {
            #pragma unroll
            for (int r = 0; r < 4; ++r) {
                int e  = mt * 16 + q8 * 4 + r;
                int nn = n0 + e;
                float xv = (nn < NN) ? x[(size_t)nn * FF + n] : 0.f;
                pre[mt][r] = xv + acc2[mt][r] + bb;
            }
        }
    }
    #pragma unroll
    for (int mt = 0; mt < 4; ++mt) {
        #pragma unroll
        for (int r = 0; r < 4; ++r) {
            float s = pre[mt][r], sq = pre[mt][r] * pre[mt][r];
            s += __shfl_xor(s, 1);  sq += __shfl_xor(sq, 1);
            s += __shfl_xor(s, 2);  sq += __shfl_xor(sq, 2);
            s += __shfl_xor(s, 4);  sq += __shfl_xor(sq, 4);
            s += __shfl_xor(s, 8);  sq += __shfl_xor(sq, 8);
            if (l15 == 0) {
                int e = mt * 16 + q8 * 4 + r;
                sRedS[w][e] = s;
                sRedQ[w][e] = sq;
            }
        }
    }
    __syncthreads();

    {
        float g = gamma[n], bt = beta[n];
        #pragma unroll
        for (int mt = 0; mt < 4; ++mt) {
            #pragma unroll
            for (int r = 0; r < 4; ++r) {
                int e  = mt * 16 + q8 * 4 + r;
                int nn = n0 + e;
                if (nn < NN) {
                    float S = 0.f, Q = 0.f;
                    #pragma unroll
                    for (int ww = 0; ww < 8; ++ww) { S += sRedS[ww][e]; Q += sRedQ[ww][e]; }
                    float mean = S * (1.f / FF);
                    float var  = Q * (1.f / FF) - mean * mean;
                    xout[(size_t)nn * FF + n] =
                        g * (pre[mt][r] - mean) * rsqrtf(var + LN_EPS) + bt;
                }
            }
        }
    }
}

// -------------------- launcher --------------------
extern "C" void kernel_launch(void* const* d_in, const int* in_sizes, int n_in,
                              void* d_out, int out_size, void* d_ws, size_t ws_size,
                              hipStream_t stream) {
    const float* x    = (const float*)d_in[0];
    const float* pos  = (const float*)d_in[1];
    const int*   ei   = (const int*)  d_in[2];
    const float* ew1  = (const float*)d_in[3];
    const float* eb1  = (const float*)d_in[4];
    const float* ew2  = (const float*)d_in[5];
    const float* eb2  = (const float*)d_in[6];
    const float* nw1  = (const float*)d_in[7];
    const float* nb1  = (const float*)d_in[8];
    const float* nw2  = (const float*)d_in[9];
    const float* nb2  = (const float*)d_in[10];
    const float* cw   = (const float*)d_in[11];
    const float* cb   = (const float*)d_in[12];
    const float* gam  = (const float*)d_in[13];
    const float* bet  = (const float*)d_in[14];

    float* out    = (float*)d_out;
    float* xout   = out;
    float* posout = out + (size_t)NN * FF;

    auto align256 = [](size_t v) { return (v + 255) & ~(size_t)255; };
    char* ws = (char*)d_ws;

    size_t CNT_B   = align256((size_t)NN * 4);
    size_t OFFS_B  = align256((size_t)NN * 4);
    size_t RST_B   = align256((size_t)NN * 4);
    size_t CHNK_B  = align256((size_t)NC * 4 * 2);
    size_t SPAIR_B = align256((size_t)EE * 8);
    size_t XB_B    = align256((size_t)NN * FF * 2);
    size_t EW1T_B  = align256((size_t)128 * 256 * 2);
    size_t WT_B    = align256((size_t)128 * 128 * 2);
    size_t Y_B     = align256((size_t)NN * 256 * 2);  // 25.6 MB bf16
    size_t AGG_B   = align256((size_t)NN * FF * 4);   // 25.6 MB f32

    size_t o = 0;
    int* cnt       = (int*)(ws + o);  o += CNT_B;    // zeroed
    int* offs      = (int*)(ws + o);  o += OFFS_B;
    int* rowStart  = (int*)(ws + o);  o += RST_B;
    int* chunkSum  = (int*)(ws + o);
    int* chunkOff  = chunkSum + NC;   o += CHNK_B;
    int2* sPair    = (int2*)(ws + o); o += SPAIR_B;
    unsigned short* xb   = (unsigned short*)(ws + o);  o += XB_B;
    unsigned short* ew1T = (unsigned short*)(ws + o);  o += EW1T_B;
    unsigned short* ew2T = (unsigned short*)(ws + o);  o += WT_B;
    unsigned short* nw1T = (unsigned short*)(ws + o);  o += WT_B;
    unsigned short* nw2T = (unsigned short*)(ws + o);  o += WT_B;
    unsigned short* Yb   = (unsigned short*)(ws + o);  o += Y_B;
    float*          agg  = (float*)(ws + o);           o += AGG_B;
    float*          sSg  = (float*)(ws + o);

    hipMemsetAsync(cnt, 0, CNT_B, stream);
    hipMemsetAsync(agg, 0, (size_t)NN * FF * 4, stream);

    prep_kernel<<<CVT_BLKS + TRW_BLKS + HIST_BLKS, 256, 0, stream>>>(
        x, xb, ew1, ew2, nw1, nw2, ew1T, ew2T, nw1T, nw2T, ei, cnt);

    nodeY_kernel<<<YNBLK, 512, 0, stream>>>(xb, ew1T, Yb);

    chunk_sum_kernel<<<NC, 256, 0, stream>>>(cnt, chunkSum);
    scan_chunks_kernel<<<1, 256, 0, stream>>>(chunkSum, chunkOff);
    scan_kernel<<<NC, 256, 0, stream>>>(cnt, chunkOff, offs, rowStart);
    scatter_idx_kernel<<<(EE + 255) / 256, 256, 0, stream>>>(ei, offs, sPair);

    edgeA_kernel<<<GRID_A, 512, 0, stream>>>(
        Yb, pos, sPair, ew1, eb1, ew2T, eb2, cw, cb, agg, sSg);

    nodeB_kernel<<<NBLK, 512, 0, stream>>>(
        x, pos, agg, sSg, sPair, rowStart,
        nw1T, nb1, nw2T, nb2, gam, bet, xout, posout);
}

// Round 14
// 448.301 us; speedup vs baseline: 1.3329x; 1.0675x over previous
//
#include <hip/hip_runtime.h>
#include <math.h>

#define NN 50000
#define EE 800000
#define FF 128

constexpr float LN_EPS = 1e-5f;
constexpr int NC = (NN + 255) / 256;   // 196 scan chunks

typedef float  f32x4  __attribute__((ext_vector_type(4)));
typedef short  s16x8  __attribute__((ext_vector_type(8)));
typedef unsigned short u16x4 __attribute__((ext_vector_type(4)));

__device__ __forceinline__ float silu_f(float v) {
    return v / (1.f + __expf(-v));
}

__device__ __forceinline__ unsigned short f2bf(float f) {
    union { float f; unsigned u; } cv; cv.f = f;
    unsigned u = cv.u;
    u += 0x7fffu + ((u >> 16) & 1u);   // round-to-nearest-even
    return (unsigned short)(u >> 16);
}

__device__ __forceinline__ float bf2f(unsigned short u) {
    union { unsigned u; float f; } cv; cv.u = ((unsigned)u) << 16;
    return cv.f;
}

// ---------- fused prep: x->bf16, weight transposes, AND row histogram -----
constexpr int CVT_BLKS  = (NN * FF / 8) / 256;       // 3125
constexpr int TRW_BLKS  = (32768 + 3 * 16384) / 256; // 320
constexpr int HIST_BLKS = (EE + 255) / 256;          // 3125

__global__ __launch_bounds__(256) void prep_kernel(
    const float* __restrict__ x, unsigned short* __restrict__ xb,
    const float* __restrict__ ew1, const float* __restrict__ ew2,
    const float* __restrict__ nw1, const float* __restrict__ nw2,
    unsigned short* __restrict__ ew1T, unsigned short* __restrict__ ew2T,
    unsigned short* __restrict__ nw1T, unsigned short* __restrict__ nw2T,
    const int* __restrict__ ei, int* __restrict__ cnt)
{
    if (blockIdx.x < CVT_BLKS) {
        int i = (blockIdx.x * 256 + threadIdx.x) * 8;
        float4 a = *(const float4*)&x[i];
        float4 b = *(const float4*)&x[i + 4];
        s16x8 o;
        o[0] = (short)f2bf(a.x); o[1] = (short)f2bf(a.y);
        o[2] = (short)f2bf(a.z); o[3] = (short)f2bf(a.w);
        o[4] = (short)f2bf(b.x); o[5] = (short)f2bf(b.y);
        o[6] = (short)f2bf(b.z); o[7] = (short)f2bf(b.w);
        *(s16x8*)&xb[i] = o;
    } else if (blockIdx.x < CVT_BLKS + TRW_BLKS) {
        int o = (blockIdx.x - CVT_BLKS) * 256 + threadIdx.x;
        if (o < 32768) {
            int n = o >> 8, k = o & 255;
            ew1T[o] = f2bf(ew1[k * FF + n]);
        } else if (o < 49152) {
            int o2 = o - 32768; int n = o2 >> 7, k = o2 & 127;
            ew2T[o2] = f2bf(ew2[k * FF + n]);
        } else if (o < 65536) {
            int o2 = o - 49152; int n = o2 >> 7, k = o2 & 127;
            nw1T[o2] = f2bf(nw1[k * FF + n]);
        } else {
            int o2 = o - 65536; int n = o2 >> 7, k = o2 & 127;
            nw2T[o2] = f2bf(nw2[k * FF + n]);
        }
    } else {
        int e = (blockIdx.x - CVT_BLKS - TRW_BLKS) * 256 + threadIdx.x;
        if (e < EE) atomicAdd(&cnt[ei[e]], 1);
    }
}

// ---------- nodeY: Y[n][0:128] = x@ew1[0:128];  Y[n][128:256] = x@ew1[128:256]
constexpr int YABS = 136;
constexpr int YNBLK = (NN + 63) / 64;   // 782

__global__ __launch_bounds__(512) void nodeY_kernel(
    const unsigned short* __restrict__ xb,
    const unsigned short* __restrict__ ew1T,
    unsigned short* __restrict__ Y)
{
    __shared__ __align__(16) unsigned short aB[64 * YABS];

    const int t   = threadIdx.x;
    const int w   = t >> 6;
    const int l   = t & 63;
    const int l15 = l & 15;
    const int q8  = l >> 4;
    const int n0  = blockIdx.x * 64;
    const int n   = w * 16 + l15;

    #pragma unroll
    for (int i = 0; i < 2; ++i) {
        int idx = (i * 512 + t) * 8;
        int e = idx >> 7, c = idx & 127;
        s16x8 v = {};
        if (n0 + e < NN) v = *(const s16x8*)(xb + (size_t)(n0 + e) * FF + c);
        *(s16x8*)(aB + e * YABS + c) = v;
    }
    __syncthreads();

    s16x8 ba[4], bb[4];
    #pragma unroll
    for (int ko = 0; ko < 4; ++ko) {
        ba[ko] = *(const s16x8*)(ew1T + (size_t)n * 256 + ko * 32 + q8 * 8);
        bb[ko] = *(const s16x8*)(ew1T + (size_t)n * 256 + 128 + ko * 32 + q8 * 8);
    }

    f32x4 acc1[4] = {}, acc2[4] = {};
    #pragma unroll
    for (int mt = 0; mt < 4; ++mt) {
        const unsigned short* ar = aB + (mt * 16 + l15) * YABS + q8 * 8;
        #pragma unroll
        for (int ko = 0; ko < 4; ++ko) {
            s16x8 a = *(const s16x8*)(ar + ko * 32);
            acc1[mt] = __builtin_amdgcn_mfma_f32_16x16x32_bf16(a, ba[ko], acc1[mt], 0, 0, 0);
            acc2[mt] = __builtin_amdgcn_mfma_f32_16x16x32_bf16(a, bb[ko], acc2[mt], 0, 0, 0);
        }
    }
    #pragma unroll
    for (int mt = 0; mt < 4; ++mt) {
        #pragma unroll
        for (int r = 0; r < 4; ++r) {
            int nn = n0 + mt * 16 + q8 * 4 + r;
            if (nn < NN) {
                Y[(size_t)nn * 256 + n]       = f2bf(acc1[mt][r]);
                Y[(size_t)nn * 256 + 128 + n] = f2bf(acc2[mt][r]);
            }
        }
    }
}

// -------------------- counting sort by row --------------------
__global__ __launch_bounds__(256) void chunk_sum_kernel(
    const int* __restrict__ cnt, int* __restrict__ chunkSum)
{
    __shared__ int s[256];
    int t = threadIdx.x;
    int idx = blockIdx.x * 256 + t;
    s[t] = (idx < NN) ? cnt[idx] : 0;
    __syncthreads();
    for (int off = 128; off > 0; off >>= 1) {
        if (t < off) s[t] += s[t + off];
        __syncthreads();
    }
    if (t == 0) chunkSum[blockIdx.x] = s[0];
}

__global__ __launch_bounds__(256) void scan_chunks_kernel(
    const int* __restrict__ chunkSum, int* __restrict__ chunkOff)
{
    __shared__ int s[256];
    int t = threadIdx.x;
    int v = (t < NC) ? chunkSum[t] : 0;
    s[t] = v;
    __syncthreads();
    for (int off = 1; off < 256; off <<= 1) {
        int u = (t >= off) ? s[t - off] : 0;
        __syncthreads();
        s[t] += u;
        __syncthreads();
    }
    if (t < NC) chunkOff[t] = s[t] - v;
}

__global__ __launch_bounds__(256) void scan_kernel(
    const int* __restrict__ cnt, const int* __restrict__ chunkOff,
    int* __restrict__ offs, int* __restrict__ rowStart)
{
    __shared__ int s[256];
    int t = threadIdx.x;
    int idx = blockIdx.x * 256 + t;
    int v = (idx < NN) ? cnt[idx] : 0;
    s[t] = v;
    __syncthreads();
    for (int off = 1; off < 256; off <<= 1) {
        int u = (t >= off) ? s[t - off] : 0;
        __syncthreads();
        s[t] += u;
        __syncthreads();
    }
    if (idx < NN) {
        int st = chunkOff[blockIdx.x] + s[t] - v;
        offs[idx] = st;
        rowStart[idx] = st;
    }
}

__global__ __launch_bounds__(256) void scatter_idx_kernel(
    const int* __restrict__ ei, int* __restrict__ offs,
    int2* __restrict__ sPair)
{
    int e = blockIdx.x * 256 + threadIdx.x;
    if (e < EE) {
        int r = ei[e], c = ei[EE + e];
        int p = atomicAdd(&offs[r], 1);
        sPair[p] = make_int2(r, c);
    }
}

// ==================== PASS A: edge MLP -> fused scatter-add ===============
constexpr int EPB    = 64;
constexpr int NTILE  = EE / EPB;    // 12500
constexpr int GRID_A = 2500;        // exactly 5 tiles per block
constexpr int H1S    = 136;         // h1 stride: 272 B row (17 quads, odd)
constexpr int MTS    = 72;          // msgT stride (144 B, straight r10 layout)

// ya LDS staging DELETED: since GEMM1 was replaced by the elementwise silu
// pass (r10), each thread consumes exactly the Y data it gathers -- so
// gather straight into registers (same 256B/16-lane coalescing). LDS drops
// 72.7KB -> 38.4KB (4 blocks/CU if VGPR<=64), and dist2 is computed
// per-thread from L2-resident pos, enabling TWO barriers per tile:
//   top: rowS[bsel] (t<64); d2 from pos; silu(yr regs) -> h1; prefetch next
//   (B) -> GEMM2 (h1); p-shuffle -> sPartT; msgT writes (straight layout)
//   (C) -> tanh (sPartT) -> sSg; segment-reduce (msgT, rowS[bsel]) -> atomics
// Hazard audit (same class as r8-r10 HW-validated):
//   h1 written top of tile i+1 -- all waves passed (C)_i, GEMM2 reads done.
//   msgT/sPartT written after (B)_{i+1}; readers (seg-reduce/tanh of tile i)
//   must reach (B)_{i+1} first -> done. rowS double-buffered [bsel].
__global__ __launch_bounds__(512, 4) void edgeA_kernel(
    const unsigned short* __restrict__ Yb, const float* __restrict__ pos,
    const int2* __restrict__ sPair,
    const float* __restrict__ ew1, const float* __restrict__ eb1,
    const unsigned short* __restrict__ ew2T, const float* __restrict__ eb2,
    const float* __restrict__ cw,  const float* __restrict__ cb,
    float* __restrict__ agg, float* __restrict__ sSg)
{
    __shared__ int   rowS[2][EPB];                             // 512 B
    __shared__ float sPartT[EPB][8];                           // 2048 B
    __shared__ __align__(16) unsigned short h1  [EPB * H1S];   // 17408 B
    __shared__ __align__(16) unsigned short msgT[FF * MTS];    // 18432 B

    const int t   = threadIdx.x;
    const int w   = t >> 6;
    const int l   = t & 63;
    const int l15 = l & 15;
    const int q8  = l >> 4;
    const int n   = w * 16 + l15;

    // XCD-chunked bijective swizzle (sorted tiles -> per-XCD row locality)
    int swz;
    {
        const int qd = GRID_A >> 3, r8 = GRID_A & 7;
        int xcd = blockIdx.x & 7, p8 = blockIdx.x >> 3;
        swz = (xcd < r8 ? xcd * (qd + 1) : r8 * (qd + 1) + (xcd - r8) * qd) + p8;
    }

    s16x8 B2[4];
    #pragma unroll
    for (int ko = 0; ko < 4; ++ko)
        B2[ko] = *(const s16x8*)(ew2T + (size_t)n * 128 + ko * 32 + q8 * 8);
    const float b2   = eb2[n];
    const float cwc  = cw[n];
    const float cb0  = cb[0];

    // silu-pass ownership: thread covers cols c8..c8+7 of edges e2, e2+1
    const int c8 = (t & 15) * 8;
    const int e2 = (t >> 4) * 2;
    float w256r[8], b1r[8];
    {
        float4 wa = *(const float4*)&ew1[256 * FF + c8];
        float4 wb = *(const float4*)&ew1[256 * FF + c8 + 4];
        w256r[0]=wa.x; w256r[1]=wa.y; w256r[2]=wa.z; w256r[3]=wa.w;
        w256r[4]=wb.x; w256r[5]=wb.y; w256r[6]=wb.z; w256r[7]=wb.w;
        float4 ca = *(const float4*)&eb1[c8];
        float4 cbv = *(const float4*)&eb1[c8 + 4];
        b1r[0]=ca.x; b1r[1]=ca.y; b1r[2]=ca.z; b1r[3]=ca.w;
        b1r[4]=cbv.x; b1r[5]=cbv.y; b1r[6]=cbv.z; b1r[7]=cbv.w;
    }

    // initial prefetch: edge pair indices + 4x16B Y gathers
    int2 prA, prB;
    s16x8 yr0, yr1, yr2, yr3;
    {
        int e0 = swz * EPB;
        prA = sPair[e0 + e2];
        prB = sPair[e0 + e2 + 1];
        yr0 = *(const s16x8*)(Yb + (size_t)prA.x * 256 + c8);
        yr1 = *(const s16x8*)(Yb + (size_t)prA.y * 256 + 128 + c8);
        yr2 = *(const s16x8*)(Yb + (size_t)prB.x * 256 + c8);
        yr3 = *(const s16x8*)(Yb + (size_t)prB.y * 256 + 128 + c8);
    }

    int bsel = 0;
    for (int tile = swz; tile < NTILE; tile += GRID_A) {
        const int e0 = tile * EPB;

        if (t < EPB) rowS[bsel][t] = sPair[e0 + t].x;

        // dist2 for this thread's 2 edges (redundant across 16-lane group;
        // pos is L2-resident, same-address lanes broadcast)
        float d2A, d2B;
        {
            float ax = pos[prA.x*3+0] - pos[prA.y*3+0];
            float ay = pos[prA.x*3+1] - pos[prA.y*3+1];
            float az = pos[prA.x*3+2] - pos[prA.y*3+2];
            d2A = ax*ax + ay*ay + az*az;
            float bx = pos[prB.x*3+0] - pos[prB.y*3+0];
            float by = pos[prB.x*3+1] - pos[prB.y*3+1];
            float bz = pos[prB.x*3+2] - pos[prB.y*3+2];
            d2B = bx*bx + by*by + bz*bz;
        }

        // silu from regs -> h1 (no ya staging)
        {
            s16x8 oA, oB;
            #pragma unroll
            for (int j = 0; j < 8; ++j) {
                float vA = bf2f((unsigned short)yr0[j]) + bf2f((unsigned short)yr1[j])
                         + d2A * w256r[j] + b1r[j];
                oA[j] = (short)f2bf(silu_f(vA));
                float vB = bf2f((unsigned short)yr2[j]) + bf2f((unsigned short)yr3[j])
                         + d2B * w256r[j] + b1r[j];
                oB[j] = (short)f2bf(silu_f(vB));
            }
            *(s16x8*)(h1 + e2 * H1S + c8)       = oA;
            *(s16x8*)(h1 + (e2 + 1) * H1S + c8) = oB;
        }

        // prefetch next tile (registers consumed above)
        {
            int tn  = tile + GRID_A;
            int e0n = (tn < NTILE) ? tn * EPB : 0;
            prA = sPair[e0n + e2];
            prB = sPair[e0n + e2 + 1];
            yr0 = *(const s16x8*)(Yb + (size_t)prA.x * 256 + c8);
            yr1 = *(const s16x8*)(Yb + (size_t)prA.y * 256 + 128 + c8);
            yr2 = *(const s16x8*)(Yb + (size_t)prB.x * 256 + c8);
            yr3 = *(const s16x8*)(Yb + (size_t)prB.y * 256 + 128 + c8);
        }
        __syncthreads();   // (B)

        f32x4 acc2[4] = {};
        #pragma unroll
        for (int mt = 0; mt < 4; ++mt) {
            const unsigned short* hr = h1 + (mt * 16 + l15) * H1S + q8 * 8;
            #pragma unroll
            for (int ko = 0; ko < 4; ++ko) {
                s16x8 a = *(const s16x8*)(hr + ko * 32);
                acc2[mt] = __builtin_amdgcn_mfma_f32_16x16x32_bf16(a, B2[ko], acc2[mt], 0, 0, 0);
            }
        }

        // p = msg.cw partial sums via shuffles (r7-r10);
        // msg -> msgT[n][e] transposed, STRAIGHT layout (r10; r12's swizzle
        // was mis-derived and doubled conflicts).
        #pragma unroll
        for (int mt = 0; mt < 4; ++mt) {
            u16x4 o;
            #pragma unroll
            for (int r = 0; r < 4; ++r) {
                float m = acc2[mt][r] + b2;
                o[r] = f2bf(m);
                float p = m * cwc;
                p += __shfl_xor(p, 1);
                p += __shfl_xor(p, 2);
                p += __shfl_xor(p, 4);
                p += __shfl_xor(p, 8);
                if (l15 == 0) sPartT[mt * 16 + q8 * 4 + r][w] = p;
            }
            *(u16x4*)(msgT + n * MTS + mt * 16 + q8 * 4) = o;
        }
        __syncthreads();   // (C)

        // ---- tanh(coord scale), all 512 threads ----
        {
            int e  = t >> 3;
            int ww = t & 7;
            float p = sPartT[e][ww];
            p += __shfl_xor(p, 1);
            p += __shfl_xor(p, 2);
            p += __shfl_xor(p, 4);
            if (ww == 0) sSg[e0 + e] = tanhf(p + cb0);
        }

        // ---- fused segment-reduce + scatter-add into agg ----
        {
            int c    = t & 127;
            int s    = t >> 7;
            int base = s * 16;
            const unsigned short* mr = msgT + c * MTS + base;
            s16x8 v0 = *(const s16x8*)(mr);
            s16x8 v1 = *(const s16x8*)(mr + 8);
            float a  = 0.f;
            int cur  = rowS[bsel][base];
            #pragma unroll
            for (int k = 0; k < 16; ++k) {
                int r = rowS[bsel][base + k];
                if (r != cur) {
                    atomicAdd(&agg[(size_t)cur * FF + c], a);
                    a = 0.f; cur = r;
                }
                unsigned short mv = (k < 8) ? (unsigned short)v0[k]
                                            : (unsigned short)v1[k - 8];
                a += bf2f(mv);
            }
            atomicAdd(&agg[(size_t)cur * FF + c], a);
        }
        bsel ^= 1;
    }
}

// ==================== PASS B: agg read + MFMA node MLP + LN + pos =========
constexpr int NPB  = 64;
constexpr int ABS  = 136;                      // bf16 LDS row stride
constexpr int NBLK = (NN + NPB - 1) / NPB;     // 782 (last block: 16 valid)

__global__ __launch_bounds__(512) void nodeB_kernel(
    const float* __restrict__ x, const float* __restrict__ pos,
    const float* __restrict__ agg, const float* __restrict__ sSg,
    const int2* __restrict__ sPair, const int* __restrict__ rowStart,
    const unsigned short* __restrict__ nw1T, const float* __restrict__ nb1,
    const unsigned short* __restrict__ nw2T, const float* __restrict__ nb2,
    const float* __restrict__ gamma, const float* __restrict__ beta,
    float* __restrict__ xout, float* __restrict__ posout)
{
    __shared__ __align__(16) unsigned short aB [NPB * ABS];   // 17408 B
    __shared__ __align__(16) unsigned short h1B[NPB * ABS];   // 17408 B
    __shared__ float sRedS[8][NPB];
    __shared__ float sRedQ[8][NPB];

    const int t   = threadIdx.x;
    const int w   = t >> 6;          // 0..7
    const int l   = t & 63;
    const int l15 = l & 15;
    const int q8  = l >> 4;          // 0..3
    const int n0  = blockIdx.x * NPB;
    const int n   = w * 16 + l15;    // this wave's output column

    // ---- load agg rows (f32) -> aB (bf16): 8192 floats, 16 per thread ----
    #pragma unroll
    for (int i = 0; i < 4; ++i) {
        int idx = (i * 512 + t) * 4;
        int e = idx >> 7, c = idx & 127;
        u16x4 o;
        if (n0 + e < NN) {
            float4 v = *(const float4*)&agg[(size_t)(n0 + e) * FF + c];
            o[0] = f2bf(v.x); o[1] = f2bf(v.y); o[2] = f2bf(v.z); o[3] = f2bf(v.w);
        } else {
            o[0] = 0; o[1] = 0; o[2] = 0; o[3] = 0;
        }
        *(u16x4*)(aB + e * ABS + c) = o;
    }

    // ---- pos update: 8 chunks per node, all 512 threads ----
    {
        int e  = t >> 3;             // 0..63
        int ch = t & 7;              // 0..7
        int nn = n0 + e;
        bool ok = nn < NN;
        int p0 = ok ? rowStart[nn] : 0;
        int p1 = ok ? ((nn == NN - 1) ? EE : rowStart[nn + 1]) : 0;
        float px = ok ? pos[nn*3+0] : 0.f;
        float py = ok ? pos[nn*3+1] : 0.f;
        float pz = ok ? pos[nn*3+2] : 0.f;
        float sx = 0.f, sy = 0.f, sz = 0.f;
        for (int p = p0 + ch; p < p1; p += 8) {
            int c = sPair[p].y;
            float g = sSg[p];
            sx += g * (px - pos[c*3+0]);
            sy += g * (py - pos[c*3+1]);
            sz += g * (pz - pos[c*3+2]);
        }
        #pragma unroll
        for (int off = 1; off < 8; off <<= 1) {
            sx += __shfl_xor(sx, off);
            sy += __shfl_xor(sy, off);
            sz += __shfl_xor(sz, off);
        }
        if (ch == 0 && ok) {
            posout[nn*3+0] = px + sx;
            posout[nn*3+1] = py + sy;
            posout[nn*3+2] = pz + sz;
        }
    }
    __syncthreads();

    // ---- GEMM1 (64 nodes x 128 cols, K=128): wave w -> 16 cols ----
    f32x4 acc[4] = {};
    {
        s16x8 bw[4];
        #pragma unroll
        for (int ko = 0; ko < 4; ++ko)
            bw[ko] = *(const s16x8*)(nw1T + (size_t)n * 128 + ko * 32 + q8 * 8);
        #pragma unroll
        for (int mt = 0; mt < 4; ++mt) {
            const unsigned short* ar = aB + (mt * 16 + l15) * ABS + q8 * 8;
            #pragma unroll
            for (int ko = 0; ko < 4; ++ko) {
                s16x8 a = *(const s16x8*)(ar + ko * 32);
                acc[mt] = __builtin_amdgcn_mfma_f32_16x16x32_bf16(a, bw[ko], acc[mt], 0, 0, 0);
            }
        }
    }
    {
        float bb = nb1[n];
        #pragma unroll
        for (int mt = 0; mt < 4; ++mt) {
            #pragma unroll
            for (int r = 0; r < 4; ++r) {
                int e = mt * 16 + q8 * 4 + r;
                h1B[e * ABS + n] = f2bf(silu_f(acc[mt][r] + bb));
            }
        }
    }
    __syncthreads();

    // ---- GEMM2 (K=128) ----
    f32x4 acc2[4] = {};
    {
        s16x8 bw[4];
        #pragma unroll
        for (int ko = 0; ko < 4; ++ko)
            bw[ko] = *(const s16x8*)(nw2T + (size_t)n * 128 + ko * 32 + q8 * 8);
        #pragma unroll
        for (int mt = 0; mt < 4; ++mt) {
            const unsigned short* hr = h1B + (mt * 16 + l15) * ABS + q8 * 8;
            #pragma unroll
            for (int ko = 0; ko < 4; ++ko) {
                s16x8 a = *(const s16x8*)(hr + ko * 32);
                acc2[mt] = __builtin_amdgcn_mfma_f32_16x16x32_bf16(a, bw[ko], acc2[mt], 0, 0, 0);
            }
        }
    }

    // ---- residual + LN ----
    float pre[4][4];
    {
        float bb = nb2[n];
        #pragma unroll
        for (int mt = 0; mt < 4; ++mt) {
            #pragma unroll
            for (int r = 0; r < 4; ++r) {
                int e  = mt * 16 + q8 * 4 + r;
                int nn = n0 + e;
                float xv = (nn < NN) ? x[(size_t)nn * FF + n] : 0.f;
                pre[mt][r] = xv + acc2[mt][r] + bb;
            }
        }
    }
    #pragma unroll
    for (int mt = 0; mt < 4; ++mt) {
        #pragma unroll
        for (int r = 0; r < 4; ++r) {
            float s = pre[mt][r], sq = pre[mt][r] * pre[mt][r];
            s += __shfl_xor(s, 1);  sq += __shfl_xor(sq, 1);
            s += __shfl_xor(s, 2);  sq += __shfl_xor(sq, 2);
            s += __shfl_xor(s, 4);  sq += __shfl_xor(sq, 4);
            s += __shfl_xor(s, 8);  sq += __shfl_xor(sq, 8);
            if (l15 == 0) {
                int e = mt * 16 + q8 * 4 + r;
                sRedS[w][e] = s;
                sRedQ[w][e] = sq;
            }
        }
    }
    __syncthreads();

    {
        float g = gamma[n], bt = beta[n];
        #pragma unroll
        for (int mt = 0; mt < 4; ++mt) {
            #pragma unroll
            for (int r = 0; r < 4; ++r) {
                int e  = mt * 16 + q8 * 4 + r;
                int nn = n0 + e;
                if (nn < NN) {
                    float S = 0.f, Q = 0.f;
                    #pragma unroll
                    for (int ww = 0; ww < 8; ++ww) { S += sRedS[ww][e]; Q += sRedQ[ww][e]; }
                    float mean = S * (1.f / FF);
                    float var  = Q * (1.f / FF) - mean * mean;
                    xout[(size_t)nn * FF + n] =
                        g * (pre[mt][r] - mean) * rsqrtf(var + LN_EPS) + bt;
                }
            }
        }
    }
}

// -------------------- launcher --------------------
extern "C" void kernel_launch(void* const* d_in, const int* in_sizes, int n_in,
                              void* d_out, int out_size, void* d_ws, size_t ws_size,
                              hipStream_t stream) {
    const float* x    = (const float*)d_in[0];
    const float* pos  = (const float*)d_in[1];
    const int*   ei   = (const int*)  d_in[2];
    const float* ew1  = (const float*)d_in[3];
    const float* eb1  = (const float*)d_in[4];
    const float* ew2  = (const float*)d_in[5];
    const float* eb2  = (const float*)d_in[6];
    const float* nw1  = (const float*)d_in[7];
    const float* nb1  = (const float*)d_in[8];
    const float* nw2  = (const float*)d_in[9];
    const float* nb2  = (const float*)d_in[10];
    const float* cw   = (const float*)d_in[11];
    const float* cb   = (const float*)d_in[12];
    const float* gam  = (const float*)d_in[13];
    const float* bet  = (const float*)d_in[14];

    float* out    = (float*)d_out;
    float* xout   = out;
    float* posout = out + (size_t)NN * FF;

    auto align256 = [](size_t v) { return (v + 255) & ~(size_t)255; };
    char* ws = (char*)d_ws;

    size_t CNT_B   = align256((size_t)NN * 4);
    size_t OFFS_B  = align256((size_t)NN * 4);
    size_t RST_B   = align256((size_t)NN * 4);
    size_t CHNK_B  = align256((size_t)NC * 4 * 2);
    size_t SPAIR_B = align256((size_t)EE * 8);
    size_t XB_B    = align256((size_t)NN * FF * 2);
    size_t EW1T_B  = align256((size_t)128 * 256 * 2);
    size_t WT_B    = align256((size_t)128 * 128 * 2);
    size_t Y_B     = align256((size_t)NN * 256 * 2);  // 25.6 MB bf16
    size_t AGG_B   = align256((size_t)NN * FF * 4);   // 25.6 MB f32

    size_t o = 0;
    int* cnt       = (int*)(ws + o);  o += CNT_B;    // zeroed
    int* offs      = (int*)(ws + o);  o += OFFS_B;
    int* rowStart  = (int*)(ws + o);  o += RST_B;
    int* chunkSum  = (int*)(ws + o);
    int* chunkOff  = chunkSum + NC;   o += CHNK_B;
    int2* sPair    = (int2*)(ws + o); o += SPAIR_B;
    unsigned short* xb   = (unsigned short*)(ws + o);  o += XB_B;
    unsigned short* ew1T = (unsigned short*)(ws + o);  o += EW1T_B;
    unsigned short* ew2T = (unsigned short*)(ws + o);  o += WT_B;
    unsigned short* nw1T = (unsigned short*)(ws + o);  o += WT_B;
    unsigned short* nw2T = (unsigned short*)(ws + o);  o += WT_B;
    unsigned short* Yb   = (unsigned short*)(ws + o);  o += Y_B;
    float*          agg  = (float*)(ws + o);           o += AGG_B;
    float*          sSg  = (float*)(ws + o);

    hipMemsetAsync(cnt, 0, CNT_B, stream);
    hipMemsetAsync(agg, 0, (size_t)NN * FF * 4, stream);

    prep_kernel<<<CVT_BLKS + TRW_BLKS + HIST_BLKS, 256, 0, stream>>>(
        x, xb, ew1, ew2, nw1, nw2, ew1T, ew2T, nw1T, nw2T, ei, cnt);

    nodeY_kernel<<<YNBLK, 512, 0, stream>>>(xb, ew1T, Yb);

    chunk_sum_kernel<<<NC, 256, 0, stream>>>(cnt, chunkSum);
    scan_chunks_kernel<<<1, 256, 0, stream>>>(chunkSum, chunkOff);
    scan_kernel<<<NC, 256, 0, stream>>>(cnt, chunkOff, offs, rowStart);
    scatter_idx_kernel<<<(EE + 255) / 256, 256, 0, stream>>>(ei, offs, sPair);

    edgeA_kernel<<<GRID_A, 512, 0, stream>>>(
        Yb, pos, sPair, ew1, eb1, ew2T, eb2, cw, cb, agg, sSg);

    nodeB_kernel<<<NBLK, 512, 0, stream>>>(
        x, pos, agg, sSg, sPair, rowStart,
        nw1T, nb1, nw2T, nb2, gam, bet, xout, posout);
}

// Round 15
// 434.761 us; speedup vs baseline: 1.3744x; 1.0311x over previous
//
#include <hip/hip_runtime.h>
#include <math.h>

#define NN 50000
#define EE 800000
#define FF 128

constexpr float LN_EPS = 1e-5f;
constexpr int NC = (NN + 255) / 256;   // 196 scan chunks

typedef float  f32x4  __attribute__((ext_vector_type(4)));
typedef short  s16x8  __attribute__((ext_vector_type(8)));
typedef unsigned short u16x4 __attribute__((ext_vector_type(4)));

__device__ __forceinline__ float silu_f(float v) {
    return v / (1.f + __expf(-v));
}

__device__ __forceinline__ unsigned short f2bf(float f) {
    union { float f; unsigned u; } cv; cv.f = f;
    unsigned u = cv.u;
    u += 0x7fffu + ((u >> 16) & 1u);   // round-to-nearest-even
    return (unsigned short)(u >> 16);
}

__device__ __forceinline__ float bf2f(unsigned short u) {
    union { unsigned u; float f; } cv; cv.u = ((unsigned)u) << 16;
    return cv.f;
}

// packed-pair unpack: 1 VALU op per element (bit-exact vs bf2f)
__device__ __forceinline__ float bfLo(unsigned d) {
    union { unsigned u; float f; } cv; cv.u = d << 16; return cv.f;
}
__device__ __forceinline__ float bfHi(unsigned d) {
    union { unsigned u; float f; } cv; cv.u = d & 0xffff0000u; return cv.f;
}

// ---------- fused prep: x->bf16, weight transposes, AND row histogram -----
constexpr int CVT_BLKS  = (NN * FF / 8) / 256;       // 3125
constexpr int TRW_BLKS  = (32768 + 3 * 16384) / 256; // 320
constexpr int HIST_BLKS = (EE + 255) / 256;          // 3125

__global__ __launch_bounds__(256) void prep_kernel(
    const float* __restrict__ x, unsigned short* __restrict__ xb,
    const float* __restrict__ ew1, const float* __restrict__ ew2,
    const float* __restrict__ nw1, const float* __restrict__ nw2,
    unsigned short* __restrict__ ew1T, unsigned short* __restrict__ ew2T,
    unsigned short* __restrict__ nw1T, unsigned short* __restrict__ nw2T,
    const int* __restrict__ ei, int* __restrict__ cnt)
{
    if (blockIdx.x < CVT_BLKS) {
        int i = (blockIdx.x * 256 + threadIdx.x) * 8;
        float4 a = *(const float4*)&x[i];
        float4 b = *(const float4*)&x[i + 4];
        s16x8 o;
        o[0] = (short)f2bf(a.x); o[1] = (short)f2bf(a.y);
        o[2] = (short)f2bf(a.z); o[3] = (short)f2bf(a.w);
        o[4] = (short)f2bf(b.x); o[5] = (short)f2bf(b.y);
        o[6] = (short)f2bf(b.z); o[7] = (short)f2bf(b.w);
        *(s16x8*)&xb[i] = o;
    } else if (blockIdx.x < CVT_BLKS + TRW_BLKS) {
        int o = (blockIdx.x - CVT_BLKS) * 256 + threadIdx.x;
        if (o < 32768) {
            int n = o >> 8, k = o & 255;
            ew1T[o] = f2bf(ew1[k * FF + n]);
        } else if (o < 49152) {
            int o2 = o - 32768; int n = o2 >> 7, k = o2 & 127;
            ew2T[o2] = f2bf(ew2[k * FF + n]);
        } else if (o < 65536) {
            int o2 = o - 49152; int n = o2 >> 7, k = o2 & 127;
            nw1T[o2] = f2bf(nw1[k * FF + n]);
        } else {
            int o2 = o - 65536; int n = o2 >> 7, k = o2 & 127;
            nw2T[o2] = f2bf(nw2[k * FF + n]);
        }
    } else {
        int e = (blockIdx.x - CVT_BLKS - TRW_BLKS) * 256 + threadIdx.x;
        if (e < EE) atomicAdd(&cnt[ei[e]], 1);
    }
}

// ---------- nodeY: Y[n][0:128] = x@ew1[0:128];  Y[n][128:256] = x@ew1[128:256]
constexpr int YABS = 136;
constexpr int YNBLK = (NN + 63) / 64;   // 782

__global__ __launch_bounds__(512) void nodeY_kernel(
    const unsigned short* __restrict__ xb,
    const unsigned short* __restrict__ ew1T,
    unsigned short* __restrict__ Y)
{
    __shared__ __align__(16) unsigned short aB[64 * YABS];

    const int t   = threadIdx.x;
    const int w   = t >> 6;
    const int l   = t & 63;
    const int l15 = l & 15;
    const int q8  = l >> 4;
    const int n0  = blockIdx.x * 64;
    const int n   = w * 16 + l15;

    #pragma unroll
    for (int i = 0; i < 2; ++i) {
        int idx = (i * 512 + t) * 8;
        int e = idx >> 7, c = idx & 127;
        s16x8 v = {};
        if (n0 + e < NN) v = *(const s16x8*)(xb + (size_t)(n0 + e) * FF + c);
        *(s16x8*)(aB + e * YABS + c) = v;
    }
    __syncthreads();

    s16x8 ba[4], bb[4];
    #pragma unroll
    for (int ko = 0; ko < 4; ++ko) {
        ba[ko] = *(const s16x8*)(ew1T + (size_t)n * 256 + ko * 32 + q8 * 8);
        bb[ko] = *(const s16x8*)(ew1T + (size_t)n * 256 + 128 + ko * 32 + q8 * 8);
    }

    f32x4 acc1[4] = {}, acc2[4] = {};
    #pragma unroll
    for (int mt = 0; mt < 4; ++mt) {
        const unsigned short* ar = aB + (mt * 16 + l15) * YABS + q8 * 8;
        #pragma unroll
        for (int ko = 0; ko < 4; ++ko) {
            s16x8 a = *(const s16x8*)(ar + ko * 32);
            acc1[mt] = __builtin_amdgcn_mfma_f32_16x16x32_bf16(a, ba[ko], acc1[mt], 0, 0, 0);
            acc2[mt] = __builtin_amdgcn_mfma_f32_16x16x32_bf16(a, bb[ko], acc2[mt], 0, 0, 0);
        }
    }
    #pragma unroll
    for (int mt = 0; mt < 4; ++mt) {
        #pragma unroll
        for (int r = 0; r < 4; ++r) {
            int nn = n0 + mt * 16 + q8 * 4 + r;
            if (nn < NN) {
                Y[(size_t)nn * 256 + n]       = f2bf(acc1[mt][r]);
                Y[(size_t)nn * 256 + 128 + n] = f2bf(acc2[mt][r]);
            }
        }
    }
}

// -------------------- counting sort by row --------------------
__global__ __launch_bounds__(256) void chunk_sum_kernel(
    const int* __restrict__ cnt, int* __restrict__ chunkSum)
{
    __shared__ int s[256];
    int t = threadIdx.x;
    int idx = blockIdx.x * 256 + t;
    s[t] = (idx < NN) ? cnt[idx] : 0;
    __syncthreads();
    for (int off = 128; off > 0; off >>= 1) {
        if (t < off) s[t] += s[t + off];
        __syncthreads();
    }
    if (t == 0) chunkSum[blockIdx.x] = s[0];
}

__global__ __launch_bounds__(256) void scan_chunks_kernel(
    const int* __restrict__ chunkSum, int* __restrict__ chunkOff)
{
    __shared__ int s[256];
    int t = threadIdx.x;
    int v = (t < NC) ? chunkSum[t] : 0;
    s[t] = v;
    __syncthreads();
    for (int off = 1; off < 256; off <<= 1) {
        int u = (t >= off) ? s[t - off] : 0;
        __syncthreads();
        s[t] += u;
        __syncthreads();
    }
    if (t < NC) chunkOff[t] = s[t] - v;
}

__global__ __launch_bounds__(256) void scan_kernel(
    const int* __restrict__ cnt, const int* __restrict__ chunkOff,
    int* __restrict__ offs, int* __restrict__ rowStart)
{
    __shared__ int s[256];
    int t = threadIdx.x;
    int idx = blockIdx.x * 256 + t;
    int v = (idx < NN) ? cnt[idx] : 0;
    s[t] = v;
    __syncthreads();
    for (int off = 1; off < 256; off <<= 1) {
        int u = (t >= off) ? s[t - off] : 0;
        __syncthreads();
        s[t] += u;
        __syncthreads();
    }
    if (idx < NN) {
        int st = chunkOff[blockIdx.x] + s[t] - v;
        offs[idx] = st;
        rowStart[idx] = st;
    }
}

__global__ __launch_bounds__(256) void scatter_idx_kernel(
    const int* __restrict__ ei, int* __restrict__ offs,
    int2* __restrict__ sPair)
{
    int e = blockIdx.x * 256 + threadIdx.x;
    if (e < EE) {
        int r = ei[e], c = ei[EE + e];
        int p = atomicAdd(&offs[r], 1);
        sPair[p] = make_int2(r, c);
    }
}

// ==================== PASS A: edge MLP -> fused scatter-add ===============
constexpr int EPB    = 64;
constexpr int NTILE  = EE / EPB;    // 12500
constexpr int GRID_A = 2500;        // exactly 5 tiles per block
constexpr int H1S    = 136;         // h1 stride: 272 B row (17 quads, odd)
constexpr int MTS    = 72;          // msgT stride (144 B, straight r10 layout)

// r14 structure (HW-verified, 448.3us) + VALU cut: packed-dword bf16 unpack
// (1 op/elem vs ~3) in the silu pass and segment-reduce, and rowS read as
// 4x ds_read_b128 (two halves, +8 VGPR liveness) instead of 16 scalar reads.
// TWO barriers per tile:
//   top: rowS[bsel] (t<64); d2 from pos; silu(yr regs) -> h1; prefetch next
//   (B) -> GEMM2 (h1); p-shuffle -> sPartT; msgT writes (straight layout)
//   (C) -> tanh (sPartT) -> sSg; segment-reduce (msgT, rowS[bsel]) -> atomics
__global__ __launch_bounds__(512, 4) void edgeA_kernel(
    const unsigned short* __restrict__ Yb, const float* __restrict__ pos,
    const int2* __restrict__ sPair,
    const float* __restrict__ ew1, const float* __restrict__ eb1,
    const unsigned short* __restrict__ ew2T, const float* __restrict__ eb2,
    const float* __restrict__ cw,  const float* __restrict__ cb,
    float* __restrict__ agg, float* __restrict__ sSg)
{
    __shared__ int   rowS[2][EPB];                             // 512 B
    __shared__ float sPartT[EPB][8];                           // 2048 B
    __shared__ __align__(16) unsigned short h1  [EPB * H1S];   // 17408 B
    __shared__ __align__(16) unsigned short msgT[FF * MTS];    // 18432 B

    const int t   = threadIdx.x;
    const int w   = t >> 6;
    const int l   = t & 63;
    const int l15 = l & 15;
    const int q8  = l >> 4;
    const int n   = w * 16 + l15;

    // XCD-chunked bijective swizzle (sorted tiles -> per-XCD row locality)
    int swz;
    {
        const int qd = GRID_A >> 3, r8 = GRID_A & 7;
        int xcd = blockIdx.x & 7, p8 = blockIdx.x >> 3;
        swz = (xcd < r8 ? xcd * (qd + 1) : r8 * (qd + 1) + (xcd - r8) * qd) + p8;
    }

    s16x8 B2[4];
    #pragma unroll
    for (int ko = 0; ko < 4; ++ko)
        B2[ko] = *(const s16x8*)(ew2T + (size_t)n * 128 + ko * 32 + q8 * 8);
    const float b2   = eb2[n];
    const float cwc  = cw[n];
    const float cb0  = cb[0];

    // silu-pass ownership: thread covers cols c8..c8+7 of edges e2, e2+1
    const int c8 = (t & 15) * 8;
    const int e2 = (t >> 4) * 2;
    float w256r[8], b1r[8];
    {
        float4 wa = *(const float4*)&ew1[256 * FF + c8];
        float4 wb = *(const float4*)&ew1[256 * FF + c8 + 4];
        w256r[0]=wa.x; w256r[1]=wa.y; w256r[2]=wa.z; w256r[3]=wa.w;
        w256r[4]=wb.x; w256r[5]=wb.y; w256r[6]=wb.z; w256r[7]=wb.w;
        float4 ca = *(const float4*)&eb1[c8];
        float4 cbv = *(const float4*)&eb1[c8 + 4];
        b1r[0]=ca.x; b1r[1]=ca.y; b1r[2]=ca.z; b1r[3]=ca.w;
        b1r[4]=cbv.x; b1r[5]=cbv.y; b1r[6]=cbv.z; b1r[7]=cbv.w;
    }

    const int q8e = t & 15;   // unused alias guard (kept minimal)

    // initial prefetch: edge pair indices + 4x16B Y gathers
    int2 prA, prB;
    s16x8 yr0, yr1, yr2, yr3;
    {
        int e0 = swz * EPB;
        prA = sPair[e0 + e2];
        prB = sPair[e0 + e2 + 1];
        yr0 = *(const s16x8*)(Yb + (size_t)prA.x * 256 + c8);
        yr1 = *(const s16x8*)(Yb + (size_t)prA.y * 256 + 128 + c8);
        yr2 = *(const s16x8*)(Yb + (size_t)prB.x * 256 + c8);
        yr3 = *(const s16x8*)(Yb + (size_t)prB.y * 256 + 128 + c8);
    }
    (void)q8e;

    int bsel = 0;
    for (int tile = swz; tile < NTILE; tile += GRID_A) {
        const int e0 = tile * EPB;

        if (t < EPB) rowS[bsel][t] = sPair[e0 + t].x;

        // dist2 for this thread's 2 edges (pos L2-resident, broadcast)
        float d2A, d2B;
        {
            float ax = pos[prA.x*3+0] - pos[prA.y*3+0];
            float ay = pos[prA.x*3+1] - pos[prA.y*3+1];
            float az = pos[prA.x*3+2] - pos[prA.y*3+2];
            d2A = ax*ax + ay*ay + az*az;
            float bx = pos[prB.x*3+0] - pos[prB.y*3+0];
            float by = pos[prB.x*3+1] - pos[prB.y*3+1];
            float bz = pos[prB.x*3+2] - pos[prB.y*3+2];
            d2B = bx*bx + by*by + bz*bz;
        }

        // silu from regs -> h1; packed-dword unpack (1 op/elem, bit-exact)
        {
            const unsigned* y0d = (const unsigned*)&yr0;
            const unsigned* y1d = (const unsigned*)&yr1;
            const unsigned* y2d = (const unsigned*)&yr2;
            const unsigned* y3d = (const unsigned*)&yr3;
            s16x8 oA, oB;
            #pragma unroll
            for (int jj = 0; jj < 4; ++jj) {
                unsigned a0 = y0d[jj], a1 = y1d[jj];
                float vLo = bfLo(a0) + bfLo(a1) + d2A * w256r[2*jj]   + b1r[2*jj];
                float vHi = bfHi(a0) + bfHi(a1) + d2A * w256r[2*jj+1] + b1r[2*jj+1];
                oA[2*jj]   = (short)f2bf(silu_f(vLo));
                oA[2*jj+1] = (short)f2bf(silu_f(vHi));
                unsigned b0 = y2d[jj], b1v = y3d[jj];
                float uLo = bfLo(b0) + bfLo(b1v) + d2B * w256r[2*jj]   + b1r[2*jj];
                float uHi = bfHi(b0) + bfHi(b1v) + d2B * w256r[2*jj+1] + b1r[2*jj+1];
                oB[2*jj]   = (short)f2bf(silu_f(uLo));
                oB[2*jj+1] = (short)f2bf(silu_f(uHi));
            }
            *(s16x8*)(h1 + e2 * H1S + c8)       = oA;
            *(s16x8*)(h1 + (e2 + 1) * H1S + c8) = oB;
        }

        // prefetch next tile (registers consumed above)
        {
            int tn  = tile + GRID_A;
            int e0n = (tn < NTILE) ? tn * EPB : 0;
            prA = sPair[e0n + e2];
            prB = sPair[e0n + e2 + 1];
            yr0 = *(const s16x8*)(Yb + (size_t)prA.x * 256 + c8);
            yr1 = *(const s16x8*)(Yb + (size_t)prA.y * 256 + 128 + c8);
            yr2 = *(const s16x8*)(Yb + (size_t)prB.x * 256 + c8);
            yr3 = *(const s16x8*)(Yb + (size_t)prB.y * 256 + 128 + c8);
        }
        __syncthreads();   // (B)

        f32x4 acc2[4] = {};
        #pragma unroll
        for (int mt = 0; mt < 4; ++mt) {
            const unsigned short* hr = h1 + (mt * 16 + l15) * H1S + q8 * 8;
            #pragma unroll
            for (int ko = 0; ko < 4; ++ko) {
                s16x8 a = *(const s16x8*)(hr + ko * 32);
                acc2[mt] = __builtin_amdgcn_mfma_f32_16x16x32_bf16(a, B2[ko], acc2[mt], 0, 0, 0);
            }
        }

        // p = msg.cw partial sums via shuffles; msgT straight layout (r10)
        #pragma unroll
        for (int mt = 0; mt < 4; ++mt) {
            u16x4 o;
            #pragma unroll
            for (int r = 0; r < 4; ++r) {
                float m = acc2[mt][r] + b2;
                o[r] = f2bf(m);
                float p = m * cwc;
                p += __shfl_xor(p, 1);
                p += __shfl_xor(p, 2);
                p += __shfl_xor(p, 4);
                p += __shfl_xor(p, 8);
                if (l15 == 0) sPartT[mt * 16 + q8 * 4 + r][w] = p;
            }
            *(u16x4*)(msgT + n * MTS + mt * 16 + q8 * 4) = o;
        }
        __syncthreads();   // (C)

        // ---- tanh(coord scale), all 512 threads ----
        {
            int e  = t >> 3;
            int ww = t & 7;
            float p = sPartT[e][ww];
            p += __shfl_xor(p, 1);
            p += __shfl_xor(p, 2);
            p += __shfl_xor(p, 4);
            if (ww == 0) sSg[e0 + e] = tanhf(p + cb0);
        }

        // ---- fused segment-reduce + scatter-add into agg ----
        // thread t: column c = t&127, edge-quarter s = t>>7 (16 edges).
        // rowS via 4x ds_read_b128 (broadcast) in two halves; msg values
        // unpacked from packed dwords (1 op/elem).
        {
            int c    = t & 127;
            int s    = t >> 7;
            int base = s * 16;
            const unsigned short* mr = msgT + c * MTS + base;
            s16x8 v0 = *(const s16x8*)(mr);
            s16x8 v1 = *(const s16x8*)(mr + 8);
            const unsigned* vd0 = (const unsigned*)&v0;
            const unsigned* vd1 = (const unsigned*)&v1;

            float a  = 0.f;
            int  cur;
            {
                int4 rwa = *(const int4*)&rowS[bsel][base];
                int4 rwb = *(const int4*)&rowS[bsel][base + 4];
                cur = rwa.x;
                #pragma unroll
                for (int k = 0; k < 8; ++k) {
                    int r = (k==0)?rwa.x:(k==1)?rwa.y:(k==2)?rwa.z:(k==3)?rwa.w
                          : (k==4)?rwb.x:(k==5)?rwb.y:(k==6)?rwb.z:rwb.w;
                    if (r != cur) {
                        atomicAdd(&agg[(size_t)cur * FF + c], a);
                        a = 0.f; cur = r;
                    }
                    unsigned d = vd0[k >> 1];
                    a += (k & 1) ? bfHi(d) : bfLo(d);
                }
            }
            {
                int4 rwc = *(const int4*)&rowS[bsel][base + 8];
                int4 rwd = *(const int4*)&rowS[bsel][base + 12];
                #pragma unroll
                for (int k = 0; k < 8; ++k) {
                    int r = (k==0)?rwc.x:(k==1)?rwc.y:(k==2)?rwc.z:(k==3)?rwc.w
                          : (k==4)?rwd.x:(k==5)?rwd.y:(k==6)?rwd.z:rwd.w;
                    if (r != cur) {
                        atomicAdd(&agg[(size_t)cur * FF + c], a);
                        a = 0.f; cur = r;
                    }
                    unsigned d = vd1[k >> 1];
                    a += (k & 1) ? bfHi(d) : bfLo(d);
                }
            }
            atomicAdd(&agg[(size_t)cur * FF + c], a);
        }
        bsel ^= 1;
    }
}

// ==================== PASS B: agg read + MFMA node MLP + LN + pos =========
constexpr int NPB  = 64;
constexpr int ABS  = 136;                      // bf16 LDS row stride
constexpr int NBLK = (NN + NPB - 1) / NPB;     // 782 (last block: 16 valid)

__global__ __launch_bounds__(512) void nodeB_kernel(
    const float* __restrict__ x, const float* __restrict__ pos,
    const float* __restrict__ agg, const float* __restrict__ sSg,
    const int2* __restrict__ sPair, const int* __restrict__ rowStart,
    const unsigned short* __restrict__ nw1T, const float* __restrict__ nb1,
    const unsigned short* __restrict__ nw2T, const float* __restrict__ nb2,
    const float* __restrict__ gamma, const float* __restrict__ beta,
    float* __restrict__ xout, float* __restrict__ posout)
{
    __shared__ __align__(16) unsigned short aB [NPB * ABS];   // 17408 B
    __shared__ __align__(16) unsigned short h1B[NPB * ABS];   // 17408 B
    __shared__ float sRedS[8][NPB];
    __shared__ float sRedQ[8][NPB];

    const int t   = threadIdx.x;
    const int w   = t >> 6;          // 0..7
    const int l   = t & 63;
    const int l15 = l & 15;
    const int q8  = l >> 4;          // 0..3
    const int n0  = blockIdx.x * NPB;
    const int n   = w * 16 + l15;    // this wave's output column

    // ---- load agg rows (f32) -> aB (bf16): 8192 floats, 16 per thread ----
    #pragma unroll
    for (int i = 0; i < 4; ++i) {
        int idx = (i * 512 + t) * 4;
        int e = idx >> 7, c = idx & 127;
        u16x4 o;
        if (n0 + e < NN) {
            float4 v = *(const float4*)&agg[(size_t)(n0 + e) * FF + c];
            o[0] = f2bf(v.x); o[1] = f2bf(v.y); o[2] = f2bf(v.z); o[3] = f2bf(v.w);
        } else {
            o[0] = 0; o[1] = 0; o[2] = 0; o[3] = 0;
        }
        *(u16x4*)(aB + e * ABS + c) = o;
    }

    // ---- pos update: 8 chunks per node, all 512 threads ----
    {
        int e  = t >> 3;             // 0..63
        int ch = t & 7;              // 0..7
        int nn = n0 + e;
        bool ok = nn < NN;
        int p0 = ok ? rowStart[nn] : 0;
        int p1 = ok ? ((nn == NN - 1) ? EE : rowStart[nn + 1]) : 0;
        float px = ok ? pos[nn*3+0] : 0.f;
        float py = ok ? pos[nn*3+1] : 0.f;
        float pz = ok ? pos[nn*3+2] : 0.f;
        float sx = 0.f, sy = 0.f, sz = 0.f;
        for (int p = p0 + ch; p < p1; p += 8) {
            int c = sPair[p].y;
            float g = sSg[p];
            sx += g * (px - pos[c*3+0]);
            sy += g * (py - pos[c*3+1]);
            sz += g * (pz - pos[c*3+2]);
        }
        #pragma unroll
        for (int off = 1; off < 8; off <<= 1) {
            sx += __shfl_xor(sx, off);
            sy += __shfl_xor(sy, off);
            sz += __shfl_xor(sz, off);
        }
        if (ch == 0 && ok) {
            posout[nn*3+0] = px + sx;
            posout[nn*3+1] = py + sy;
            posout[nn*3+2] = pz + sz;
        }
    }
    __syncthreads();

    // ---- GEMM1 (64 nodes x 128 cols, K=128): wave w -> 16 cols ----
    f32x4 acc[4] = {};
    {
        s16x8 bw[4];
        #pragma unroll
        for (int ko = 0; ko < 4; ++ko)
            bw[ko] = *(const s16x8*)(nw1T + (size_t)n * 128 + ko * 32 + q8 * 8);
        #pragma unroll
        for (int mt = 0; mt < 4; ++mt) {
            const unsigned short* ar = aB + (mt * 16 + l15) * ABS + q8 * 8;
            #pragma unroll
            for (int ko = 0; ko < 4; ++ko) {
                s16x8 a = *(const s16x8*)(ar + ko * 32);
                acc[mt] = __builtin_amdgcn_mfma_f32_16x16x32_bf16(a, bw[ko], acc[mt], 0, 0, 0);
            }
        }
    }
    {
        float bb = nb1[n];
        #pragma unroll
        for (int mt = 0; mt < 4; ++mt) {
            #pragma unroll
            for (int r = 0; r < 4; ++r) {
                int e = mt * 16 + q8 * 4 + r;
                h1B[e * ABS + n] = f2bf(silu_f(acc[mt][r] + bb));
            }
        }
    }
    __syncthreads();

    // ---- GEMM2 (K=128) ----
    f32x4 acc2[4] = {};
    {
        s16x8 bw[4];
        #pragma unroll
        for (int ko = 0; ko < 4; ++ko)
            bw[ko] = *(const s16x8*)(nw2T + (size_t)n * 128 + ko * 32 + q8 * 8);
        #pragma unroll
        for (int mt = 0; mt < 4; ++mt) {
            const unsigned short* hr = h1B + (mt * 16 + l15) * ABS + q8 * 8;
            #pragma unroll
            for (int ko = 0; ko < 4; ++ko) {
                s16x8 a = *(const s16x8*)(hr + ko * 32);
                acc2[mt] = __builtin_amdgcn_mfma_f32_16x16x32_bf16(a, bw[ko], acc2[mt], 0, 0, 0);
            }
        }
    }

    // ---- residual + LN ----
    float pre[4][4];
    {
        float bb = nb2[n];
        #pragma unroll
        for (int mt = 0; mt < 4; ++mt) {
            #pragma unroll
            for (int r = 0; r < 4; ++r) {
                int e  = mt * 16 + q8 * 4 + r;
                int nn = n0 + e;
                float xv = (nn < NN) ? x[(size_t)nn * FF + n] : 0.f;
                pre[mt][r] = xv + acc2[mt][r] + bb;
            }
        }
    }
    #pragma unroll
    for (int mt = 0; mt < 4; ++mt) {
        #pragma unroll
        for (int r = 0; r < 4; ++r) {
            float s = pre[mt][r], sq = pre[mt][r] * pre[mt][r];
            s += __shfl_xor(s, 1);  sq += __shfl_xor(sq, 1);
            s += __shfl_xor(s, 2);  sq += __shfl_xor(sq, 2);
            s += __shfl_xor(s, 4);  sq += __shfl_xor(sq, 4);
            s += __shfl_xor(s, 8);  sq += __shfl_xor(sq, 8);
            if (l15 == 0) {
                int e = mt * 16 + q8 * 4 + r;
                sRedS[w][e] = s;
                sRedQ[w][e] = sq;
            }
        }
    }
    __syncthreads();

    {
        float g = gamma[n], bt = beta[n];
        #pragma unroll
        for (int mt = 0; mt < 4; ++mt) {
            #pragma unroll
            for (int r = 0; r < 4; ++r) {
                int e  = mt * 16 + q8 * 4 + r;
                int nn = n0 + e;
                if (nn < NN) {
                    float S = 0.f, Q = 0.f;
                    #pragma unroll
                    for (int ww = 0; ww < 8; ++ww) { S += sRedS[ww][e]; Q += sRedQ[ww][e]; }
                    float mean = S * (1.f / FF);
                    float var  = Q * (1.f / FF) - mean * mean;
                    xout[(size_t)nn * FF + n] =
                        g * (pre[mt][r] - mean) * rsqrtf(var + LN_EPS) + bt;
                }
            }
        }
    }
}

// -------------------- launcher --------------------
extern "C" void kernel_launch(void* const* d_in, const int* in_sizes, int n_in,
                              void* d_out, int out_size, void* d_ws, size_t ws_size,
                              hipStream_t stream) {
    const float* x    = (const float*)d_in[0];
    const float* pos  = (const float*)d_in[1];
    const int*   ei   = (const int*)  d_in[2];
    const float* ew1  = (const float*)d_in[3];
    const float* eb1  = (const float*)d_in[4];
    const float* ew2  = (const float*)d_in[5];
    const float* eb2  = (const float*)d_in[6];
    const float* nw1  = (const float*)d_in[7];
    const float* nb1  = (const float*)d_in[8];
    const float* nw2  = (const float*)d_in[9];
    const float* nb2  = (const float*)d_in[10];
    const float* cw   = (const float*)d_in[11];
    const float* cb   = (const float*)d_in[12];
    const float* gam  = (const float*)d_in[13];
    const float* bet  = (const float*)d_in[14];

    float* out    = (float*)d_out;
    float* xout   = out;
    float* posout = out + (size_t)NN * FF;

    auto align256 = [](size_t v) { return (v + 255) & ~(size_t)255; };
    char* ws = (char*)d_ws;

    size_t CNT_B   = align256((size_t)NN * 4);
    size_t OFFS_B  = align256((size_t)NN * 4);
    size_t RST_B   = align256((size_t)NN * 4);
    size_t CHNK_B  = align256((size_t)NC * 4 * 2);
    size_t SPAIR_B = align256((size_t)EE * 8);
    size_t XB_B    = align256((size_t)NN * FF * 2);
    size_t EW1T_B  = align256((size_t)128 * 256 * 2);
    size_t WT_B    = align256((size_t)128 * 128 * 2);
    size_t Y_B     = align256((size_t)NN * 256 * 2);  // 25.6 MB bf16
    size_t AGG_B   = align256((size_t)NN * FF * 4);   // 25.6 MB f32

    size_t o = 0;
    int* cnt       = (int*)(ws + o);  o += CNT_B;    // zeroed
    int* offs      = (int*)(ws + o);  o += OFFS_B;
    int* rowStart  = (int*)(ws + o);  o += RST_B;
    int* chunkSum  = (int*)(ws + o);
    int* chunkOff  = chunkSum + NC;   o += CHNK_B;
    int2* sPair    = (int2*)(ws + o); o += SPAIR_B;
    unsigned short* xb   = (unsigned short*)(ws + o);  o += XB_B;
    unsigned short* ew1T = (unsigned short*)(ws + o);  o += EW1T_B;
    unsigned short* ew2T = (unsigned short*)(ws + o);  o += WT_B;
    unsigned short* nw1T = (unsigned short*)(ws + o);  o += WT_B;
    unsigned short* nw2T = (unsigned short*)(ws + o);  o += WT_B;
    unsigned short* Yb   = (unsigned short*)(ws + o);  o += Y_B;
    float*          agg  = (float*)(ws + o);           o += AGG_B;
    float*          sSg  = (float*)(ws + o);

    hipMemsetAsync(cnt, 0, CNT_B, stream);
    hipMemsetAsync(agg, 0, (size_t)NN * FF * 4, stream);

    prep_kernel<<<CVT_BLKS + TRW_BLKS + HIST_BLKS, 256, 0, stream>>>(
        x, xb, ew1, ew2, nw1, nw2, ew1T, ew2T, nw1T, nw2T, ei, cnt);

    nodeY_kernel<<<YNBLK, 512, 0, stream>>>(xb, ew1T, Yb);

    chunk_sum_kernel<<<NC, 256, 0, stream>>>(cnt, chunkSum);
    scan_chunks_kernel<<<1, 256, 0, stream>>>(chunkSum, chunkOff);
    scan_kernel<<<NC, 256, 0, stream>>>(cnt, chunkOff, offs, rowStart);
    scatter_idx_kernel<<<(EE + 255) / 256, 256, 0, stream>>>(ei, offs, sPair);

    edgeA_kernel<<<GRID_A, 512, 0, stream>>>(
        Yb, pos, sPair, ew1, eb1, ew2T, eb2, cw, cb, agg, sSg);

    nodeB_kernel<<<NBLK, 512, 0, stream>>>(
        x, pos, agg, sSg, sPair, rowStart,
        nw1T, nb1, nw2T, nb2, gam, bet, xout, posout);
}